// Round 2
// baseline (501.335 us; speedup 1.0000x reference)
//
#include <hip/hip_runtime.h>
#include <math.h>

#define N_NODES 50000
#define N_EDGES 800000
#define N_CAND  100000
#define D       128
#define BN_EPS  1e-5f
#define SLOPE   0.01f

__device__ __forceinline__ float lrelu(float x){ return x >= 0.f ? x : SLOPE * x; }

// ---------------- CSR build ----------------
__global__ __launch_bounds__(256) void k_hist(const int* __restrict__ dst, int* __restrict__ cnt, int E){
  int i = blockIdx.x * 256 + threadIdx.x;
  if (i < E) atomicAdd(&cnt[dst[i]], 1);
}

__global__ __launch_bounds__(256) void k_scan1(const int* __restrict__ cnt, int* __restrict__ rowptr,
                                               int* __restrict__ bsum, int n){
  __shared__ int sd[256];
  int t = threadIdx.x; int i = blockIdx.x * 256 + t;
  int v = (i < n) ? cnt[i] : 0;
  sd[t] = v; __syncthreads();
  for (int off = 1; off < 256; off <<= 1){
    int add = (t >= off) ? sd[t - off] : 0;
    __syncthreads();
    sd[t] += add; __syncthreads();
  }
  if (i < n) rowptr[i] = sd[t] - v;          // exclusive within block
  if (t == 255) bsum[blockIdx.x] = sd[255];  // block total
}

__global__ __launch_bounds__(256) void k_scan2(int* __restrict__ bsum, int* __restrict__ rowptr, int nb, int n){
  __shared__ int sd[256];
  int t = threadIdx.x;
  int v = (t < nb) ? bsum[t] : 0;
  sd[t] = v; __syncthreads();
  for (int off = 1; off < 256; off <<= 1){
    int add = (t >= off) ? sd[t - off] : 0;
    __syncthreads();
    sd[t] += add; __syncthreads();
  }
  if (t < nb) bsum[t] = sd[t] - v;           // exclusive block offsets
  if (t == nb - 1) rowptr[n] = sd[t];        // total = E
}

__global__ __launch_bounds__(256) void k_scan3(int* __restrict__ rowptr, const int* __restrict__ bsum, int n){
  int i = blockIdx.x * 256 + threadIdx.x;
  if (i < n) rowptr[i] += bsum[blockIdx.x];
}

__global__ __launch_bounds__(256) void k_fill(const int* __restrict__ src, const int* __restrict__ dst,
                                              const int* __restrict__ rowptr, int* __restrict__ cur,
                                              int* __restrict__ eid, int E){
  int i = blockIdx.x * 256 + threadIdx.x;
  if (i < E){
    int d = dst[i];
    int p = atomicAdd(&cur[d], 1);
    eid[rowptr[d] + p] = src[i];
  }
}

// ---------------- mean aggregation (gather-sum over CSR) ----------------
__global__ __launch_bounds__(256) void k_agg(const float* __restrict__ X, const int* __restrict__ rowptr,
                                             const int* __restrict__ eid, float* __restrict__ AG, int n){
  int g = blockIdx.x * 8 + (threadIdx.x >> 5);   // node, 32 lanes per node
  int l = threadIdx.x & 31;                      // float4 chunk
  if (g >= n) return;
  int e0 = rowptr[g], e1 = rowptr[g + 1];
  float4 acc = make_float4(0.f, 0.f, 0.f, 0.f);
  for (int e = e0; e < e1; ++e){
    int s = eid[e];
    const float4 v = *reinterpret_cast<const float4*>(&X[(size_t)s * D + l * 4]);
    acc.x += v.x; acc.y += v.y; acc.z += v.z; acc.w += v.w;
  }
  float sc = 1.f / fmaxf((float)(e1 - e0), 1.f);
  acc.x *= sc; acc.y *= sc; acc.z *= sc; acc.w *= sc;
  *reinterpret_cast<float4*>(&AG[(size_t)g * D + l * 4]) = acc;
}

// ---------------- SAGE layer: H = lrelu(BN(X@WS + AG@WN + B)) ----------------
// 32 nodes/block, 256 threads, 4x4 microtile per thread.
__global__ __launch_bounds__(256) void k_sage(const float* __restrict__ X, const float* __restrict__ AG,
    const float* __restrict__ WS, const float* __restrict__ WN,
    const float* __restrict__ B,  const float* __restrict__ GM, const float* __restrict__ BT,
    const float* __restrict__ RM, const float* __restrict__ RV,
    float* __restrict__ H, int n, int donan)
{
  __shared__ float xs[D][36];   // transposed A tiles, pad 36 keeps 16B alignment, conflict-light
  __shared__ float as_[D][36];
  int t = threadIdx.x;
  int node0 = blockIdx.x * 32;
  {
    int row = t >> 3;    // 0..31 node in tile
    int cb  = t & 7;     // float4 column base
    for (int c4 = cb; c4 < 32; c4 += 8){
      int node = node0 + row;
      float4 v = make_float4(0.f,0.f,0.f,0.f), a = make_float4(0.f,0.f,0.f,0.f);
      if (node < n){
        v = *reinterpret_cast<const float4*>(&X [(size_t)node * D + c4 * 4]);
        a = *reinterpret_cast<const float4*>(&AG[(size_t)node * D + c4 * 4]);
      }
      xs [c4*4+0][row] = v.x; xs [c4*4+1][row] = v.y; xs [c4*4+2][row] = v.z; xs [c4*4+3][row] = v.w;
      as_[c4*4+0][row] = a.x; as_[c4*4+1][row] = a.y; as_[c4*4+2][row] = a.z; as_[c4*4+3][row] = a.w;
    }
  }
  __syncthreads();

  int tcol = t & 31, trow = t >> 5;   // trow 0..7 -> nodes trow*4..+3 ; tcol -> cols tcol*4..+3
  float acc[4][4] = {};
  #pragma unroll 2
  for (int k = 0; k < D; ++k){
    float4 av = *reinterpret_cast<const float4*>(&xs [k][trow * 4]);
    float4 gv = *reinterpret_cast<const float4*>(&as_[k][trow * 4]);
    float4 ws = *reinterpret_cast<const float4*>(&WS[k * D + tcol * 4]);
    float4 wn = *reinterpret_cast<const float4*>(&WN[k * D + tcol * 4]);
    const float* ap = (const float*)&av; const float* gp = (const float*)&gv;
    const float* wp = (const float*)&ws; const float* np = (const float*)&wn;
    #pragma unroll
    for (int m = 0; m < 4; ++m){
      #pragma unroll
      for (int j = 0; j < 4; ++j)
        acc[m][j] = fmaf(ap[m], wp[j], fmaf(gp[m], np[j], acc[m][j]));
    }
  }

  // epilogue: fold bias + BN, then leaky relu (+ nan_to_num for layer 2)
  float sj[4], cj[4];
  #pragma unroll
  for (int j = 0; j < 4; ++j){
    int col = tcol * 4 + j;
    float s = GM[col] * rsqrtf(RV[col] + BN_EPS);
    sj[j] = s;
    cj[j] = (B[col] - RM[col]) * s + BT[col];
  }
  #pragma unroll
  for (int m = 0; m < 4; ++m){
    int node = node0 + trow * 4 + m;
    if (node < n){
      float4 o; float* op = (float*)&o;
      #pragma unroll
      for (int j = 0; j < 4; ++j){
        float v = lrelu(acc[m][j] * sj[j] + cj[j]);
        if (donan && (v != v)) v = 1e-14f;
        op[j] = v;
      }
      *reinterpret_cast<float4*>(&H[(size_t)node * D + tcol * 4]) = o;
    }
  }
}

// ---------------- candidate MLP: [h_u, h_v, feat] (257) -> 64 -> 64 -> 1 ----------------
// One wave per block; lane = candidate. The 64-wide hidden layers are split
// into 4 passes of 16 outputs so the live accumulator set is 16 VGPRs (the
// round-0 version kept 128 live floats -> scratch spill, VALUBusy 21%).
// Layer-1 activations z[64] are parked in LDS ([64][65] pad -> bank (lane+k)%32,
// conflict-free); each lane reads only its own row so no barrier is needed.
// Weight indices are lane-uniform -> s_load_dwordx16 broadcasts (free vs VALU).
__global__ __launch_bounds__(64) void k_mlp(const float* __restrict__ H,
    const int* __restrict__ cu, const int* __restrict__ cv, const float* __restrict__ cf,
    const float* __restrict__ mw0, const float* __restrict__ mb0,
    const float* __restrict__ mw1, const float* __restrict__ mb1,
    const float* __restrict__ mw2, const float* __restrict__ mb2,
    float* __restrict__ y, int C)
{
  __shared__ float z[64][65];
  int t = threadIdx.x;
  int c  = blockIdx.x * 64 + t;
  int cc = min(c, C - 1);                 // clamp tail; stores are guarded below
  const float* hu = &H[(size_t)cu[cc] * D];
  const float* hv = &H[(size_t)cv[cc] * D];
  float cfv = cf[cc];

  // ---- layer 1: 257 -> 64, four passes of 16 outputs ----
  #pragma unroll
  for (int jg = 0; jg < 4; ++jg){
    float acc[16];
    #pragma unroll
    for (int j = 0; j < 16; ++j) acc[j] = mb0[jg * 16 + j];

    for (int k4 = 0; k4 < 32; ++k4){
      float4 u4 = *reinterpret_cast<const float4*>(&hu[k4 * 4]);
      const float* up = (const float*)&u4;
      #pragma unroll
      for (int i = 0; i < 4; ++i){
        float ak = up[i]; const float* wrow = &mw0[(k4 * 4 + i) * 64 + jg * 16];
        #pragma unroll
        for (int j = 0; j < 16; ++j) acc[j] = fmaf(ak, wrow[j], acc[j]);
      }
    }
    for (int k4 = 0; k4 < 32; ++k4){
      float4 v4 = *reinterpret_cast<const float4*>(&hv[k4 * 4]);
      const float* vp = (const float*)&v4;
      #pragma unroll
      for (int i = 0; i < 4; ++i){
        float ak = vp[i]; const float* wrow = &mw0[(128 + k4 * 4 + i) * 64 + jg * 16];
        #pragma unroll
        for (int j = 0; j < 16; ++j) acc[j] = fmaf(ak, wrow[j], acc[j]);
      }
    }
    {
      const float* wrow = &mw0[256 * 64 + jg * 16];
      #pragma unroll
      for (int j = 0; j < 16; ++j) acc[j] = fmaf(cfv, wrow[j], acc[j]);
    }
    #pragma unroll
    for (int j = 0; j < 16; ++j) z[t][jg * 16 + j] = lrelu(acc[j]);
  }

  // ---- layer 2 (64 -> 64) fused with layer 3 (64 -> 1) ----
  float yv = mb2[0];
  #pragma unroll
  for (int jg = 0; jg < 4; ++jg){
    float acc[16];
    #pragma unroll
    for (int j = 0; j < 16; ++j) acc[j] = mb1[jg * 16 + j];
    for (int k = 0; k < 64; ++k){
      float zk = z[t][k];
      const float* wrow = &mw1[k * 64 + jg * 16];
      #pragma unroll
      for (int j = 0; j < 16; ++j) acc[j] = fmaf(zk, wrow[j], acc[j]);
    }
    const float* w2 = &mw2[jg * 16];
    #pragma unroll
    for (int j = 0; j < 16; ++j) yv = fmaf(lrelu(acc[j]), w2[j], yv);
  }

  if (c < C) y[c] = yv;
}

// ---------------- softmax over C logits ----------------
__global__ __launch_bounds__(256) void k_red1(const float* __restrict__ y,
                                              float* __restrict__ bmax, float* __restrict__ bsum, int C){
  __shared__ float sm[4];
  __shared__ float ss[4];
  int t = threadIdx.x;
  float m = -3.4e38f;
  for (int i = blockIdx.x * 256 + t; i < C; i += gridDim.x * 256) m = fmaxf(m, y[i]);
  for (int o = 32; o; o >>= 1) m = fmaxf(m, __shfl_xor(m, o));
  if ((t & 63) == 0) sm[t >> 6] = m;
  __syncthreads();
  float bm = fmaxf(fmaxf(sm[0], sm[1]), fmaxf(sm[2], sm[3]));
  float s = 0.f;
  for (int i = blockIdx.x * 256 + t; i < C; i += gridDim.x * 256) s += expf(y[i] - bm);
  for (int o = 32; o; o >>= 1) s += __shfl_xor(s, o);
  if ((t & 63) == 0) ss[t >> 6] = s;
  __syncthreads();
  if (t == 0){ bmax[blockIdx.x] = bm; bsum[blockIdx.x] = ss[0] + ss[1] + ss[2] + ss[3]; }
}

__global__ __launch_bounds__(256) void k_red2(const float* __restrict__ bmax, const float* __restrict__ bsum,
                                              float* __restrict__ g, int nb){
  __shared__ float sm[4];
  __shared__ float ss[4];
  int t = threadIdx.x;
  float m0 = (t < nb) ? bmax[t] : -3.4e38f;
  float m = m0;
  for (int o = 32; o; o >>= 1) m = fmaxf(m, __shfl_xor(m, o));
  if ((t & 63) == 0) sm[t >> 6] = m;
  __syncthreads();
  float gm = fmaxf(fmaxf(sm[0], sm[1]), fmaxf(sm[2], sm[3]));
  float s = (t < nb) ? bsum[t] * expf(m0 - gm) : 0.f;
  for (int o = 32; o; o >>= 1) s += __shfl_xor(s, o);
  if ((t & 63) == 0) ss[t >> 6] = s;
  __syncthreads();
  if (t == 0){ g[0] = gm; g[1] = 1.f / (ss[0] + ss[1] + ss[2] + ss[3]); }
}

__global__ __launch_bounds__(256) void k_red3(const float* __restrict__ y, const float* __restrict__ g,
                                              float* __restrict__ out, int C){
  int i = blockIdx.x * 256 + threadIdx.x;
  if (i < C) out[i] = expf(y[i] - g[0]) * g[1];
}

extern "C" void kernel_launch(void* const* d_in, const int* in_sizes, int n_in,
                              void* d_out, int out_size, void* d_ws, size_t ws_size,
                              hipStream_t stream)
{
  const float* x   = (const float*)d_in[0];
  const int*   src = (const int*)  d_in[1];
  const int*   dst = (const int*)  d_in[2];
  const int*   cu  = (const int*)  d_in[3];
  const int*   cv  = (const int*)  d_in[4];
  const float* cf  = (const float*)d_in[5];
  const float* ws0 = (const float*)d_in[6];
  const float* wn0 = (const float*)d_in[7];
  const float* b0  = (const float*)d_in[8];
  const float* g0  = (const float*)d_in[9];
  const float* be0 = (const float*)d_in[10];
  const float* rm0 = (const float*)d_in[11];
  const float* rv0 = (const float*)d_in[12];
  const float* ws1 = (const float*)d_in[13];
  const float* wn1 = (const float*)d_in[14];
  const float* b1  = (const float*)d_in[15];
  const float* g1  = (const float*)d_in[16];
  const float* be1 = (const float*)d_in[17];
  const float* rm1 = (const float*)d_in[18];
  const float* rv1 = (const float*)d_in[19];
  const float* mw0 = (const float*)d_in[20];
  const float* mb0 = (const float*)d_in[21];
  const float* mw1 = (const float*)d_in[22];
  const float* mb1 = (const float*)d_in[23];
  const float* mw2 = (const float*)d_in[24];
  const float* mb2 = (const float*)d_in[25];

  float* out = (float*)d_out;   // [C] y then [C] softmax

  char* w = (char*)d_ws;
  float* aggn  = (float*)w; w += (size_t)N_NODES * D * 4;
  float* h0    = (float*)w; w += (size_t)N_NODES * D * 4;
  float* h1    = (float*)w; w += (size_t)N_NODES * D * 4;
  int* cnt     = (int*)w;   w += (size_t)N_NODES * 4;
  int* rowptr  = (int*)w;   w += (size_t)(N_NODES + 1) * 4;
  int* cur     = (int*)w;   w += (size_t)N_NODES * 4;
  int* eid     = (int*)w;   w += (size_t)N_EDGES * 4;
  int* bsumI   = (int*)w;   w += 256 * 4;
  float* bmax  = (float*)w; w += 256 * 4;
  float* bsumF = (float*)w; w += 256 * 4;
  float* gred  = (float*)w; w += 2 * 4;

  hipMemsetAsync(cnt, 0, (size_t)N_NODES * 4, stream);
  hipMemsetAsync(cur, 0, (size_t)N_NODES * 4, stream);

  int SB = (N_NODES + 255) / 256;   // 196
  k_hist <<<(N_EDGES + 255) / 256, 256, 0, stream>>>(dst, cnt, N_EDGES);
  k_scan1<<<SB, 256, 0, stream>>>(cnt, rowptr, bsumI, N_NODES);
  k_scan2<<<1, 256, 0, stream>>>(bsumI, rowptr, SB, N_NODES);
  k_scan3<<<SB, 256, 0, stream>>>(rowptr, bsumI, N_NODES);
  k_fill <<<(N_EDGES + 255) / 256, 256, 0, stream>>>(src, dst, rowptr, cur, eid, N_EDGES);

  k_agg <<<(N_NODES + 7) / 8, 256, 0, stream>>>(x, rowptr, eid, aggn, N_NODES);
  k_sage<<<(N_NODES + 31) / 32, 256, 0, stream>>>(x, aggn, ws0, wn0, b0, g0, be0, rm0, rv0, h0, N_NODES, 0);
  k_agg <<<(N_NODES + 7) / 8, 256, 0, stream>>>(h0, rowptr, eid, aggn, N_NODES);
  k_sage<<<(N_NODES + 31) / 32, 256, 0, stream>>>(h0, aggn, ws1, wn1, b1, g1, be1, rm1, rv1, h1, N_NODES, 1);

  k_mlp <<<(N_CAND + 63) / 64, 64, 0, stream>>>(h1, cu, cv, cf, mw0, mb0, mw1, mb1, mw2, mb2, out, N_CAND);

  k_red1<<<256, 256, 0, stream>>>(out, bmax, bsumF, N_CAND);
  k_red2<<<1, 256, 0, stream>>>(bmax, bsumF, gred, 256);
  k_red3<<<(N_CAND + 255) / 256, 256, 0, stream>>>(out, gred, out + N_CAND, N_CAND);
}

// Round 3
// 434.275 us; speedup vs baseline: 1.1544x; 1.1544x over previous
//
#include <hip/hip_runtime.h>
#include <math.h>

#define N_NODES 50000
#define N_EDGES 800000
#define N_CAND  100000
#define D       128
#define BN_EPS  1e-5f
#define SLOPE   0.01f

__device__ __forceinline__ float lrelu(float x){ return x >= 0.f ? x : SLOPE * x; }

// ---------------- CSR build ----------------
__global__ __launch_bounds__(256) void k_hist(const int* __restrict__ dst, int* __restrict__ cnt, int E){
  int i = blockIdx.x * 256 + threadIdx.x;
  if (i < E) atomicAdd(&cnt[dst[i]], 1);
}

__global__ __launch_bounds__(256) void k_scan1(const int* __restrict__ cnt, int* __restrict__ rowptr,
                                               int* __restrict__ bsum, int n){
  __shared__ int sd[256];
  int t = threadIdx.x; int i = blockIdx.x * 256 + t;
  int v = (i < n) ? cnt[i] : 0;
  sd[t] = v; __syncthreads();
  for (int off = 1; off < 256; off <<= 1){
    int add = (t >= off) ? sd[t - off] : 0;
    __syncthreads();
    sd[t] += add; __syncthreads();
  }
  if (i < n) rowptr[i] = sd[t] - v;          // exclusive within block
  if (t == 255) bsum[blockIdx.x] = sd[255];  // block total
}

__global__ __launch_bounds__(256) void k_scan2(int* __restrict__ bsum, int* __restrict__ rowptr, int nb, int n){
  __shared__ int sd[256];
  int t = threadIdx.x;
  int v = (t < nb) ? bsum[t] : 0;
  sd[t] = v; __syncthreads();
  for (int off = 1; off < 256; off <<= 1){
    int add = (t >= off) ? sd[t - off] : 0;
    __syncthreads();
    sd[t] += add; __syncthreads();
  }
  if (t < nb) bsum[t] = sd[t] - v;           // exclusive block offsets
  if (t == nb - 1) rowptr[n] = sd[t];        // total = E
}

__global__ __launch_bounds__(256) void k_scan3(int* __restrict__ rowptr, const int* __restrict__ bsum, int n){
  int i = blockIdx.x * 256 + threadIdx.x;
  if (i < n) rowptr[i] += bsum[blockIdx.x];
}

__global__ __launch_bounds__(256) void k_fill(const int* __restrict__ src, const int* __restrict__ dst,
                                              const int* __restrict__ rowptr, int* __restrict__ cur,
                                              int* __restrict__ eid, int E){
  int i = blockIdx.x * 256 + threadIdx.x;
  if (i < E){
    int d = dst[i];
    int p = atomicAdd(&cur[d], 1);
    eid[rowptr[d] + p] = src[i];
  }
}

// ---------------- mean aggregation (gather-sum over CSR) ----------------
__global__ __launch_bounds__(256) void k_agg(const float* __restrict__ X, const int* __restrict__ rowptr,
                                             const int* __restrict__ eid, float* __restrict__ AG, int n){
  int g = blockIdx.x * 8 + (threadIdx.x >> 5);   // node, 32 lanes per node
  int l = threadIdx.x & 31;                      // float4 chunk
  if (g >= n) return;
  int e0 = rowptr[g], e1 = rowptr[g + 1];
  float4 acc = make_float4(0.f, 0.f, 0.f, 0.f);
  for (int e = e0; e < e1; ++e){
    int s = eid[e];
    const float4 v = *reinterpret_cast<const float4*>(&X[(size_t)s * D + l * 4]);
    acc.x += v.x; acc.y += v.y; acc.z += v.z; acc.w += v.w;
  }
  float sc = 1.f / fmaxf((float)(e1 - e0), 1.f);
  acc.x *= sc; acc.y *= sc; acc.z *= sc; acc.w *= sc;
  *reinterpret_cast<float4*>(&AG[(size_t)g * D + l * 4]) = acc;
}

// ---------------- SAGE layer: H = lrelu(BN(X@WS + AG@WN + B)) ----------------
// 32 nodes/block, 256 threads, 4x4 microtile per thread.
__global__ __launch_bounds__(256) void k_sage(const float* __restrict__ X, const float* __restrict__ AG,
    const float* __restrict__ WS, const float* __restrict__ WN,
    const float* __restrict__ B,  const float* __restrict__ GM, const float* __restrict__ BT,
    const float* __restrict__ RM, const float* __restrict__ RV,
    float* __restrict__ H, int n, int donan)
{
  __shared__ float xs[D][36];   // transposed A tiles, pad 36 keeps 16B alignment, conflict-light
  __shared__ float as_[D][36];
  int t = threadIdx.x;
  int node0 = blockIdx.x * 32;
  {
    int row = t >> 3;    // 0..31 node in tile
    int cb  = t & 7;     // float4 column base
    for (int c4 = cb; c4 < 32; c4 += 8){
      int node = node0 + row;
      float4 v = make_float4(0.f,0.f,0.f,0.f), a = make_float4(0.f,0.f,0.f,0.f);
      if (node < n){
        v = *reinterpret_cast<const float4*>(&X [(size_t)node * D + c4 * 4]);
        a = *reinterpret_cast<const float4*>(&AG[(size_t)node * D + c4 * 4]);
      }
      xs [c4*4+0][row] = v.x; xs [c4*4+1][row] = v.y; xs [c4*4+2][row] = v.z; xs [c4*4+3][row] = v.w;
      as_[c4*4+0][row] = a.x; as_[c4*4+1][row] = a.y; as_[c4*4+2][row] = a.z; as_[c4*4+3][row] = a.w;
    }
  }
  __syncthreads();

  int tcol = t & 31, trow = t >> 5;   // trow 0..7 -> nodes trow*4..+3 ; tcol -> cols tcol*4..+3
  float acc[4][4] = {};
  #pragma unroll 2
  for (int k = 0; k < D; ++k){
    float4 av = *reinterpret_cast<const float4*>(&xs [k][trow * 4]);
    float4 gv = *reinterpret_cast<const float4*>(&as_[k][trow * 4]);
    float4 ws = *reinterpret_cast<const float4*>(&WS[k * D + tcol * 4]);
    float4 wn = *reinterpret_cast<const float4*>(&WN[k * D + tcol * 4]);
    const float* ap = (const float*)&av; const float* gp = (const float*)&gv;
    const float* wp = (const float*)&ws; const float* np = (const float*)&wn;
    #pragma unroll
    for (int m = 0; m < 4; ++m){
      #pragma unroll
      for (int j = 0; j < 4; ++j)
        acc[m][j] = fmaf(ap[m], wp[j], fmaf(gp[m], np[j], acc[m][j]));
    }
  }

  // epilogue: fold bias + BN, then leaky relu (+ nan_to_num for layer 2)
  float sj[4], cj[4];
  #pragma unroll
  for (int j = 0; j < 4; ++j){
    int col = tcol * 4 + j;
    float s = GM[col] * rsqrtf(RV[col] + BN_EPS);
    sj[j] = s;
    cj[j] = (B[col] - RM[col]) * s + BT[col];
  }
  #pragma unroll
  for (int m = 0; m < 4; ++m){
    int node = node0 + trow * 4 + m;
    if (node < n){
      float4 o; float* op = (float*)&o;
      #pragma unroll
      for (int j = 0; j < 4; ++j){
        float v = lrelu(acc[m][j] * sj[j] + cj[j]);
        if (donan && (v != v)) v = 1e-14f;
        op[j] = v;
      }
      *reinterpret_cast<float4*>(&H[(size_t)node * D + tcol * 4]) = o;
    }
  }
}

// ---------------- candidate MLP: [h_u, h_v, feat] (257) -> 64 -> 64 -> 1 ----------------
// Block = 256 threads (4 waves) x 64 candidates. lane = candidate.
// Wave w computes outputs [w*16, w*16+16): weight addresses are wave-uniform
// (forced via readfirstlane) -> s_load broadcasts over the scalar pipe; no LDS
// and no VGPR cost for weights. Candidate activations are staged in LDS ONCE
// per block (round-2 version re-gathered them 4x -> 175MB HBM fetch), in 4
// K-chunks of 64 (as_[k][cand], consecutive-lane access = conflict-free).
// Live accumulator set is 16 VGPRs -> no scratch spill.
__global__ __launch_bounds__(256) void k_mlp(const float* __restrict__ H,
    const int* __restrict__ cu, const int* __restrict__ cv, const float* __restrict__ cf,
    const float* __restrict__ mw0, const float* __restrict__ mb0,
    const float* __restrict__ mw1, const float* __restrict__ mb1,
    const float* __restrict__ mw2, const float* __restrict__ mb2,
    float* __restrict__ y, int C)
{
  __shared__ float as_[64][68];   // activation K-chunk, transposed [k][cand]
  __shared__ float zs_[64][68];   // layer-1 activations   [j][cand]
  __shared__ float part[4][64];   // layer-3 partial sums
  __shared__ float cfs[64];
  __shared__ int   ids[128];      // u nodes then v nodes

  int t = threadIdx.x;
  int lane = t & 63;
  int wv = __builtin_amdgcn_readfirstlane(t >> 6);   // wave id 0..3 (SGPR)
  int cand0 = blockIdx.x * 64;

  if (t < 64){
    int cc = min(cand0 + t, C - 1);
    ids[t] = cu[cc];
    cfs[t] = cf[cc];
  } else if (t < 128){
    int cc = min(cand0 + (t - 64), C - 1);
    ids[t] = cv[cc];
  }

  // ---- layer 1: 257 -> 64 ----
  float acc[16];
  {
    const float* b0p = &mb0[wv * 16];
    #pragma unroll
    for (int j = 0; j < 16; ++j) acc[j] = b0p[j];
  }

  for (int kc = 0; kc < 4; ++kc){
    __syncthreads();            // previous chunk fully consumed (also covers ids/cfs on kc=0)
    {                           // stage chunk: 64 k x 64 cand
      int cand = t & 63;
      int q    = t >> 6;        // 0..3
      int node = ids[(kc < 2 ? 0 : 64) + cand];
      const float* hrow = &H[(size_t)node * D + (kc & 1) * 64];
      #pragma unroll
      for (int p = 0; p < 4; ++p){
        int k4 = q * 4 + p;     // float4 index 0..15
        float4 v = *reinterpret_cast<const float4*>(&hrow[k4 * 4]);
        as_[k4 * 4 + 0][cand] = v.x;
        as_[k4 * 4 + 1][cand] = v.y;
        as_[k4 * 4 + 2][cand] = v.z;
        as_[k4 * 4 + 3][cand] = v.w;
      }
    }
    __syncthreads();

    const float* wbase = &mw0[(size_t)(kc * 64) * 64 + wv * 16];
    #pragma unroll 4
    for (int k = 0; k < 64; ++k){
      float a = as_[k][lane];
      const float* wrow = wbase + (size_t)k * 64;
      #pragma unroll
      for (int j = 0; j < 16; ++j) acc[j] = fmaf(a, wrow[j], acc[j]);
    }
  }
  {  // feat term (k = 256)
    float a = cfs[lane];
    const float* wrow = &mw0[256 * 64 + wv * 16];
    #pragma unroll
    for (int j = 0; j < 16; ++j) acc[j] = fmaf(a, wrow[j], acc[j]);
  }
  #pragma unroll
  for (int j = 0; j < 16; ++j) zs_[wv * 16 + j][lane] = lrelu(acc[j]);
  __syncthreads();

  // ---- layer 2: 64 -> 64 ----
  float a2[16];
  {
    const float* b1p = &mb1[wv * 16];
    #pragma unroll
    for (int j = 0; j < 16; ++j) a2[j] = b1p[j];
  }
  {
    const float* wbase = &mw1[wv * 16];
    #pragma unroll 4
    for (int k = 0; k < 64; ++k){
      float zk = zs_[k][lane];
      const float* wrow = wbase + (size_t)k * 64;
      #pragma unroll
      for (int j = 0; j < 16; ++j) a2[j] = fmaf(zk, wrow[j], a2[j]);
    }
  }

  // ---- layer 3: 64 -> 1 (partial per wave, reduce via LDS) ----
  {
    const float* w2 = &mw2[wv * 16];
    float pw = 0.f;
    #pragma unroll
    for (int j = 0; j < 16; ++j) pw = fmaf(lrelu(a2[j]), w2[j], pw);
    part[wv][lane] = pw;
  }
  __syncthreads();
  if (t < 64){
    float yv = mb2[0] + part[0][t] + part[1][t] + part[2][t] + part[3][t];
    int c = cand0 + t;
    if (c < C) y[c] = yv;
  }
}

// ---------------- softmax over C logits ----------------
__global__ __launch_bounds__(256) void k_red1(const float* __restrict__ y,
                                              float* __restrict__ bmax, float* __restrict__ bsum, int C){
  __shared__ float sm[4];
  __shared__ float ss[4];
  int t = threadIdx.x;
  float m = -3.4e38f;
  for (int i = blockIdx.x * 256 + t; i < C; i += gridDim.x * 256) m = fmaxf(m, y[i]);
  for (int o = 32; o; o >>= 1) m = fmaxf(m, __shfl_xor(m, o));
  if ((t & 63) == 0) sm[t >> 6] = m;
  __syncthreads();
  float bm = fmaxf(fmaxf(sm[0], sm[1]), fmaxf(sm[2], sm[3]));
  float s = 0.f;
  for (int i = blockIdx.x * 256 + t; i < C; i += gridDim.x * 256) s += expf(y[i] - bm);
  for (int o = 32; o; o >>= 1) s += __shfl_xor(s, o);
  if ((t & 63) == 0) ss[t >> 6] = s;
  __syncthreads();
  if (t == 0){ bmax[blockIdx.x] = bm; bsum[blockIdx.x] = ss[0] + ss[1] + ss[2] + ss[3]; }
}

__global__ __launch_bounds__(256) void k_red2(const float* __restrict__ bmax, const float* __restrict__ bsum,
                                              float* __restrict__ g, int nb){
  __shared__ float sm[4];
  __shared__ float ss[4];
  int t = threadIdx.x;
  float m0 = (t < nb) ? bmax[t] : -3.4e38f;
  float m = m0;
  for (int o = 32; o; o >>= 1) m = fmaxf(m, __shfl_xor(m, o));
  if ((t & 63) == 0) sm[t >> 6] = m;
  __syncthreads();
  float gm = fmaxf(fmaxf(sm[0], sm[1]), fmaxf(sm[2], sm[3]));
  float s = (t < nb) ? bsum[t] * expf(m0 - gm) : 0.f;
  for (int o = 32; o; o >>= 1) s += __shfl_xor(s, o);
  if ((t & 63) == 0) ss[t >> 6] = s;
  __syncthreads();
  if (t == 0){ g[0] = gm; g[1] = 1.f / (ss[0] + ss[1] + ss[2] + ss[3]); }
}

__global__ __launch_bounds__(256) void k_red3(const float* __restrict__ y, const float* __restrict__ g,
                                              float* __restrict__ out, int C){
  int i = blockIdx.x * 256 + threadIdx.x;
  if (i < C) out[i] = expf(y[i] - g[0]) * g[1];
}

extern "C" void kernel_launch(void* const* d_in, const int* in_sizes, int n_in,
                              void* d_out, int out_size, void* d_ws, size_t ws_size,
                              hipStream_t stream)
{
  const float* x   = (const float*)d_in[0];
  const int*   src = (const int*)  d_in[1];
  const int*   dst = (const int*)  d_in[2];
  const int*   cu  = (const int*)  d_in[3];
  const int*   cv  = (const int*)  d_in[4];
  const float* cf  = (const float*)d_in[5];
  const float* ws0 = (const float*)d_in[6];
  const float* wn0 = (const float*)d_in[7];
  const float* b0  = (const float*)d_in[8];
  const float* g0  = (const float*)d_in[9];
  const float* be0 = (const float*)d_in[10];
  const float* rm0 = (const float*)d_in[11];
  const float* rv0 = (const float*)d_in[12];
  const float* ws1 = (const float*)d_in[13];
  const float* wn1 = (const float*)d_in[14];
  const float* b1  = (const float*)d_in[15];
  const float* g1  = (const float*)d_in[16];
  const float* be1 = (const float*)d_in[17];
  const float* rm1 = (const float*)d_in[18];
  const float* rv1 = (const float*)d_in[19];
  const float* mw0 = (const float*)d_in[20];
  const float* mb0 = (const float*)d_in[21];
  const float* mw1 = (const float*)d_in[22];
  const float* mb1 = (const float*)d_in[23];
  const float* mw2 = (const float*)d_in[24];
  const float* mb2 = (const float*)d_in[25];

  float* out = (float*)d_out;   // [C] y then [C] softmax

  char* w = (char*)d_ws;
  float* aggn  = (float*)w; w += (size_t)N_NODES * D * 4;
  float* h0    = (float*)w; w += (size_t)N_NODES * D * 4;
  float* h1    = (float*)w; w += (size_t)N_NODES * D * 4;
  int* cnt     = (int*)w;   w += (size_t)N_NODES * 4;
  int* rowptr  = (int*)w;   w += (size_t)(N_NODES + 1) * 4;
  int* cur     = (int*)w;   w += (size_t)N_NODES * 4;
  int* eid     = (int*)w;   w += (size_t)N_EDGES * 4;
  int* bsumI   = (int*)w;   w += 256 * 4;
  float* bmax  = (float*)w; w += 256 * 4;
  float* bsumF = (float*)w; w += 256 * 4;
  float* gred  = (float*)w; w += 2 * 4;

  hipMemsetAsync(cnt, 0, (size_t)N_NODES * 4, stream);
  hipMemsetAsync(cur, 0, (size_t)N_NODES * 4, stream);

  int SB = (N_NODES + 255) / 256;   // 196
  k_hist <<<(N_EDGES + 255) / 256, 256, 0, stream>>>(dst, cnt, N_EDGES);
  k_scan1<<<SB, 256, 0, stream>>>(cnt, rowptr, bsumI, N_NODES);
  k_scan2<<<1, 256, 0, stream>>>(bsumI, rowptr, SB, N_NODES);
  k_scan3<<<SB, 256, 0, stream>>>(rowptr, bsumI, N_NODES);
  k_fill <<<(N_EDGES + 255) / 256, 256, 0, stream>>>(src, dst, rowptr, cur, eid, N_EDGES);

  k_agg <<<(N_NODES + 7) / 8, 256, 0, stream>>>(x, rowptr, eid, aggn, N_NODES);
  k_sage<<<(N_NODES + 31) / 32, 256, 0, stream>>>(x, aggn, ws0, wn0, b0, g0, be0, rm0, rv0, h0, N_NODES, 0);
  k_agg <<<(N_NODES + 7) / 8, 256, 0, stream>>>(h0, rowptr, eid, aggn, N_NODES);
  k_sage<<<(N_NODES + 31) / 32, 256, 0, stream>>>(h0, aggn, ws1, wn1, b1, g1, be1, rm1, rv1, h1, N_NODES, 1);

  k_mlp <<<(N_CAND + 63) / 64, 256, 0, stream>>>(h1, cu, cv, cf, mw0, mb0, mw1, mb1, mw2, mb2, out, N_CAND);

  k_red1<<<256, 256, 0, stream>>>(out, bmax, bsumF, N_CAND);
  k_red2<<<1, 256, 0, stream>>>(bmax, bsumF, gred, 256);
  k_red3<<<(N_CAND + 255) / 256, 256, 0, stream>>>(out, gred, out + N_CAND, N_CAND);
}

// Round 4
// 357.674 us; speedup vs baseline: 1.4017x; 1.2142x over previous
//
#include <hip/hip_runtime.h>
#include <math.h>

#define N_NODES 50000
#define N_EDGES 800000
#define N_CAND  100000
#define D       128
#define BN_EPS  1e-5f
#define SLOPE   0.01f

typedef __attribute__((ext_vector_type(8))) short bf16x8;
typedef __attribute__((ext_vector_type(4))) float f32x4;

__device__ __forceinline__ float lrelu(float x){ return x >= 0.f ? x : SLOPE * x; }

__device__ __forceinline__ unsigned short f2bf_rn(float f){
  unsigned int u = __float_as_uint(f);
  unsigned int r = u + 0x7FFFu + ((u >> 16) & 1u);
  return (unsigned short)(r >> 16);
}
__device__ __forceinline__ float bf2f(unsigned short h){
  return __uint_as_float(((unsigned int)h) << 16);
}

// ---------------- CSR build ----------------
__global__ __launch_bounds__(256) void k_hist(const int* __restrict__ dst, int* __restrict__ cnt, int E){
  int i = blockIdx.x * 256 + threadIdx.x;
  if (i < E) atomicAdd(&cnt[dst[i]], 1);
}

__global__ __launch_bounds__(256) void k_scan1(const int* __restrict__ cnt, int* __restrict__ rowptr,
                                               int* __restrict__ bsum, int n){
  __shared__ int sd[256];
  int t = threadIdx.x; int i = blockIdx.x * 256 + t;
  int v = (i < n) ? cnt[i] : 0;
  sd[t] = v; __syncthreads();
  for (int off = 1; off < 256; off <<= 1){
    int add = (t >= off) ? sd[t - off] : 0;
    __syncthreads();
    sd[t] += add; __syncthreads();
  }
  if (i < n) rowptr[i] = sd[t] - v;          // exclusive within block
  if (t == 255) bsum[blockIdx.x] = sd[255];  // block total
}

__global__ __launch_bounds__(256) void k_scan2(int* __restrict__ bsum, int* __restrict__ rowptr, int nb, int n){
  __shared__ int sd[256];
  int t = threadIdx.x;
  int v = (t < nb) ? bsum[t] : 0;
  sd[t] = v; __syncthreads();
  for (int off = 1; off < 256; off <<= 1){
    int add = (t >= off) ? sd[t - off] : 0;
    __syncthreads();
    sd[t] += add; __syncthreads();
  }
  if (t < nb) bsum[t] = sd[t] - v;           // exclusive block offsets
  if (t == nb - 1) rowptr[n] = sd[t];        // total = E
}

__global__ __launch_bounds__(256) void k_scan3(int* __restrict__ rowptr, const int* __restrict__ bsum, int n){
  int i = blockIdx.x * 256 + threadIdx.x;
  if (i < n) rowptr[i] += bsum[blockIdx.x];
}

__global__ __launch_bounds__(256) void k_fill(const int* __restrict__ src, const int* __restrict__ dst,
                                              const int* __restrict__ rowptr, int* __restrict__ cur,
                                              int* __restrict__ eid, int E){
  int i = blockIdx.x * 256 + threadIdx.x;
  if (i < E){
    int d = dst[i];
    int p = atomicAdd(&cur[d], 1);
    eid[rowptr[d] + p] = src[i];
  }
}

// ---------------- weight transpose + bf16 hi/lo split ----------------
// Wcat = [WS ; WN] (256 x 128, row-major k x col) ->  BT_h/BT_l [col][k] (128 x 256)
__global__ __launch_bounds__(256) void k_cvt_w(const float* __restrict__ ws, const float* __restrict__ wn,
                                               unsigned short* __restrict__ bth, unsigned short* __restrict__ btl){
  int col = blockIdx.x;       // 0..127
  int k   = threadIdx.x;      // 0..255
  float v = (k < 128) ? ws[k * D + col] : wn[(k - 128) * D + col];
  unsigned short hi = f2bf_rn(v);
  unsigned short lo = f2bf_rn(v - bf2f(hi));
  bth[col * 256 + k] = hi;
  btl[col * 256 + k] = lo;
}

// ---------------- mean aggregation (gather-sum over CSR) ----------------
__global__ __launch_bounds__(256) void k_agg(const float* __restrict__ X, const int* __restrict__ rowptr,
                                             const int* __restrict__ eid, float* __restrict__ AG, int n){
  int g = blockIdx.x * 8 + (threadIdx.x >> 5);   // node, 32 lanes per node
  int l = threadIdx.x & 31;                      // float4 chunk
  if (g >= n) return;
  int e0 = rowptr[g], e1 = rowptr[g + 1];
  float4 acc = make_float4(0.f, 0.f, 0.f, 0.f);
  for (int e = e0; e < e1; ++e){
    int s = eid[e];
    const float4 v = *reinterpret_cast<const float4*>(&X[(size_t)s * D + l * 4]);
    acc.x += v.x; acc.y += v.y; acc.z += v.z; acc.w += v.w;
  }
  float sc = 1.f / fmaxf((float)(e1 - e0), 1.f);
  acc.x *= sc; acc.y *= sc; acc.z *= sc; acc.w *= sc;
  *reinterpret_cast<float4*>(&AG[(size_t)g * D + l * 4]) = acc;
}

// ---------------- SAGE layer via split-bf16 MFMA ----------------
// H = lrelu(BN([X | AG] @ [WS;WN] + b)), M-tile 64 nodes x 128 cols per block.
// A (fp32) is staged to LDS with on-the-fly bf16 hi/lo split; W comes
// pre-transposed/split (BT_h/BT_l, [col][k]).  3 MFMA terms per fragment:
// Ah*Bh + Ah*Bl + Al*Bh (Al*Bl dropped, ~2^-18 relative).
// LDS rows padded to 40 elems (80 B): b128 frag reads 16B-aligned, 2-way bank
// alias only (free).  mfma_f32_16x16x32_bf16: A lane=row(l&15),k=8*(l>>4)+j;
// B lane=col(l&15); C/D col=l&15, row=(l>>4)*4+reg (m89/m91-verified).
__global__ __launch_bounds__(256) void k_sage_mfma(const float* __restrict__ XS, const float* __restrict__ AG,
    const unsigned short* __restrict__ BTH, const unsigned short* __restrict__ BTL,
    const float* __restrict__ Bb, const float* __restrict__ GM, const float* __restrict__ BT,
    const float* __restrict__ RM, const float* __restrict__ RV,
    float* __restrict__ H, int n, int donan)
{
  __shared__ unsigned short Ah[64 * 40];
  __shared__ unsigned short Al[64 * 40];
  __shared__ unsigned short Bh[128 * 40];
  __shared__ unsigned short Bl[128 * 40];

  int t  = threadIdx.x;
  int l  = t & 63;
  int wv = t >> 6;          // wave 0..3 -> rows wv*16..+15
  int lm = l & 15;          // frag row (A) / col (B,D)
  int lk = l >> 4;          // k-group 0..3
  int node0 = blockIdx.x * 64;

  f32x4 acc[8];
  #pragma unroll
  for (int f = 0; f < 8; ++f) acc[f] = (f32x4){0.f, 0.f, 0.f, 0.f};

  for (int step = 0; step < 8; ++step){
    int k0 = step * 32;                          // global k in [0,256)
    const float* srcA = (step < 4) ? XS : AG;
    int koff = (step < 4) ? k0 : (k0 - 128);

    __syncthreads();
    // ---- stage A: 64 rows x 32 k fp32 -> hi/lo bf16 (512 float4 chunks) ----
    #pragma unroll
    for (int i = 0; i < 2; ++i){
      int c   = t + i * 256;
      int row = c >> 3, c4 = c & 7;
      int node = min(node0 + row, n - 1);
      float4 v = *reinterpret_cast<const float4*>(&srcA[(size_t)node * D + koff + c4 * 4]);
      const float* vp = (const float*)&v;
      unsigned short hh[4], ll[4];
      #pragma unroll
      for (int j = 0; j < 4; ++j){
        unsigned short hi = f2bf_rn(vp[j]);
        hh[j] = hi;
        ll[j] = f2bf_rn(vp[j] - bf2f(hi));
      }
      uint2 wh, wl;
      wh.x = (unsigned)hh[0] | ((unsigned)hh[1] << 16);
      wh.y = (unsigned)hh[2] | ((unsigned)hh[3] << 16);
      wl.x = (unsigned)ll[0] | ((unsigned)ll[1] << 16);
      wl.y = (unsigned)ll[2] | ((unsigned)ll[3] << 16);
      *reinterpret_cast<uint2*>(&Ah[row * 40 + c4 * 4]) = wh;
      *reinterpret_cast<uint2*>(&Al[row * 40 + c4 * 4]) = wl;
    }
    // ---- stage B: 128 cols x 32 k bf16 hi+lo (512 16B chunks each) ----
    #pragma unroll
    for (int i = 0; i < 2; ++i){
      int c   = t + i * 256;
      int col = c >> 2, q = c & 3;
      *reinterpret_cast<uint4*>(&Bh[col * 40 + q * 8]) =
          *reinterpret_cast<const uint4*>(&BTH[col * 256 + k0 + q * 8]);
      *reinterpret_cast<uint4*>(&Bl[col * 40 + q * 8]) =
          *reinterpret_cast<const uint4*>(&BTL[col * 256 + k0 + q * 8]);
    }
    __syncthreads();

    // ---- MFMA: 8 col-frags x 3 split terms ----
    bf16x8 afh = *reinterpret_cast<const bf16x8*>(&Ah[(wv * 16 + lm) * 40 + lk * 8]);
    bf16x8 afl = *reinterpret_cast<const bf16x8*>(&Al[(wv * 16 + lm) * 40 + lk * 8]);
    #pragma unroll
    for (int f = 0; f < 8; ++f){
      bf16x8 bfh = *reinterpret_cast<const bf16x8*>(&Bh[(f * 16 + lm) * 40 + lk * 8]);
      bf16x8 bfl = *reinterpret_cast<const bf16x8*>(&Bl[(f * 16 + lm) * 40 + lk * 8]);
      acc[f] = __builtin_amdgcn_mfma_f32_16x16x32_bf16(afh, bfh, acc[f], 0, 0, 0);
      acc[f] = __builtin_amdgcn_mfma_f32_16x16x32_bf16(afl, bfh, acc[f], 0, 0, 0);
      acc[f] = __builtin_amdgcn_mfma_f32_16x16x32_bf16(afh, bfl, acc[f], 0, 0, 0);
    }
  }

  // ---- epilogue: BN + leaky relu (+ nan_to_num layer 2) ----
  #pragma unroll
  for (int f = 0; f < 8; ++f){
    int col = f * 16 + lm;
    float s  = GM[col] * rsqrtf(RV[col] + BN_EPS);
    float cj = (Bb[col] - RM[col]) * s + BT[col];
    #pragma unroll
    for (int r = 0; r < 4; ++r){
      int node = node0 + wv * 16 + lk * 4 + r;
      if (node < n){
        float v = lrelu(acc[f][r] * s + cj);
        if (donan && (v != v)) v = 1e-14f;
        H[(size_t)node * D + col] = v;
      }
    }
  }
}

// ---------------- candidate MLP: [h_u, h_v, feat] (257) -> 64 -> 64 -> 1 ----------------
// Block = 256 threads (4 waves) x 64 candidates. lane = candidate.
// Wave w computes outputs [w*16, w*16+16): weight addresses are wave-uniform
// -> s_load broadcasts; activations staged in LDS once per block.
__global__ __launch_bounds__(256) void k_mlp(const float* __restrict__ H,
    const int* __restrict__ cu, const int* __restrict__ cv, const float* __restrict__ cf,
    const float* __restrict__ mw0, const float* __restrict__ mb0,
    const float* __restrict__ mw1, const float* __restrict__ mb1,
    const float* __restrict__ mw2, const float* __restrict__ mb2,
    float* __restrict__ y, int C)
{
  __shared__ float as_[64][68];   // activation K-chunk, transposed [k][cand]
  __shared__ float zs_[64][68];   // layer-1 activations   [j][cand]
  __shared__ float part[4][64];   // layer-3 partial sums
  __shared__ float cfs[64];
  __shared__ int   ids[128];      // u nodes then v nodes

  int t = threadIdx.x;
  int lane = t & 63;
  int wv = __builtin_amdgcn_readfirstlane(t >> 6);   // wave id 0..3 (SGPR)
  int cand0 = blockIdx.x * 64;

  if (t < 64){
    int cc = min(cand0 + t, C - 1);
    ids[t] = cu[cc];
    cfs[t] = cf[cc];
  } else if (t < 128){
    int cc = min(cand0 + (t - 64), C - 1);
    ids[t] = cv[cc];
  }

  // ---- layer 1: 257 -> 64 ----
  float acc[16];
  {
    const float* b0p = &mb0[wv * 16];
    #pragma unroll
    for (int j = 0; j < 16; ++j) acc[j] = b0p[j];
  }

  for (int kc = 0; kc < 4; ++kc){
    __syncthreads();            // previous chunk fully consumed (also covers ids/cfs on kc=0)
    {                           // stage chunk: 64 k x 64 cand
      int cand = t & 63;
      int q    = t >> 6;        // 0..3
      int node = ids[(kc < 2 ? 0 : 64) + cand];
      const float* hrow = &H[(size_t)node * D + (kc & 1) * 64];
      #pragma unroll
      for (int p = 0; p < 4; ++p){
        int k4 = q * 4 + p;     // float4 index 0..15
        float4 v = *reinterpret_cast<const float4*>(&hrow[k4 * 4]);
        as_[k4 * 4 + 0][cand] = v.x;
        as_[k4 * 4 + 1][cand] = v.y;
        as_[k4 * 4 + 2][cand] = v.z;
        as_[k4 * 4 + 3][cand] = v.w;
      }
    }
    __syncthreads();

    const float* wbase = &mw0[(size_t)(kc * 64) * 64 + wv * 16];
    #pragma unroll 4
    for (int k = 0; k < 64; ++k){
      float a = as_[k][lane];
      const float* wrow = wbase + (size_t)k * 64;
      #pragma unroll
      for (int j = 0; j < 16; ++j) acc[j] = fmaf(a, wrow[j], acc[j]);
    }
  }
  {  // feat term (k = 256)
    float a = cfs[lane];
    const float* wrow = &mw0[256 * 64 + wv * 16];
    #pragma unroll
    for (int j = 0; j < 16; ++j) acc[j] = fmaf(a, wrow[j], acc[j]);
  }
  #pragma unroll
  for (int j = 0; j < 16; ++j) zs_[wv * 16 + j][lane] = lrelu(acc[j]);
  __syncthreads();

  // ---- layer 2: 64 -> 64 ----
  float a2[16];
  {
    const float* b1p = &mb1[wv * 16];
    #pragma unroll
    for (int j = 0; j < 16; ++j) a2[j] = b1p[j];
  }
  {
    const float* wbase = &mw1[wv * 16];
    #pragma unroll 4
    for (int k = 0; k < 64; ++k){
      float zk = zs_[k][lane];
      const float* wrow = wbase + (size_t)k * 64;
      #pragma unroll
      for (int j = 0; j < 16; ++j) a2[j] = fmaf(zk, wrow[j], a2[j]);
    }
  }

  // ---- layer 3: 64 -> 1 (partial per wave, reduce via LDS) ----
  {
    const float* w2 = &mw2[wv * 16];
    float pw = 0.f;
    #pragma unroll
    for (int j = 0; j < 16; ++j) pw = fmaf(lrelu(a2[j]), w2[j], pw);
    part[wv][lane] = pw;
  }
  __syncthreads();
  if (t < 64){
    float yv = mb2[0] + part[0][t] + part[1][t] + part[2][t] + part[3][t];
    int c = cand0 + t;
    if (c < C) y[c] = yv;
  }
}

// ---------------- softmax over C logits ----------------
__global__ __launch_bounds__(256) void k_red1(const float* __restrict__ y,
                                              float* __restrict__ bmax, float* __restrict__ bsum, int C){
  __shared__ float sm[4];
  __shared__ float ss[4];
  int t = threadIdx.x;
  float m = -3.4e38f;
  for (int i = blockIdx.x * 256 + t; i < C; i += gridDim.x * 256) m = fmaxf(m, y[i]);
  for (int o = 32; o; o >>= 1) m = fmaxf(m, __shfl_xor(m, o));
  if ((t & 63) == 0) sm[t >> 6] = m;
  __syncthreads();
  float bm = fmaxf(fmaxf(sm[0], sm[1]), fmaxf(sm[2], sm[3]));
  float s = 0.f;
  for (int i = blockIdx.x * 256 + t; i < C; i += gridDim.x * 256) s += expf(y[i] - bm);
  for (int o = 32; o; o >>= 1) s += __shfl_xor(s, o);
  if ((t & 63) == 0) ss[t >> 6] = s;
  __syncthreads();
  if (t == 0){ bmax[blockIdx.x] = bm; bsum[blockIdx.x] = ss[0] + ss[1] + ss[2] + ss[3]; }
}

__global__ __launch_bounds__(256) void k_red2(const float* __restrict__ bmax, const float* __restrict__ bsum,
                                              float* __restrict__ g, int nb){
  __shared__ float sm[4];
  __shared__ float ss[4];
  int t = threadIdx.x;
  float m0 = (t < nb) ? bmax[t] : -3.4e38f;
  float m = m0;
  for (int o = 32; o; o >>= 1) m = fmaxf(m, __shfl_xor(m, o));
  if ((t & 63) == 0) sm[t >> 6] = m;
  __syncthreads();
  float gm = fmaxf(fmaxf(sm[0], sm[1]), fmaxf(sm[2], sm[3]));
  float s = (t < nb) ? bsum[t] * expf(m0 - gm) : 0.f;
  for (int o = 32; o; o >>= 1) s += __shfl_xor(s, o);
  if ((t & 63) == 0) ss[t >> 6] = s;
  __syncthreads();
  if (t == 0){ g[0] = gm; g[1] = 1.f / (ss[0] + ss[1] + ss[2] + ss[3]); }
}

__global__ __launch_bounds__(256) void k_red3(const float* __restrict__ y, const float* __restrict__ g,
                                              float* __restrict__ out, int C){
  int i = blockIdx.x * 256 + threadIdx.x;
  if (i < C) out[i] = expf(y[i] - g[0]) * g[1];
}

extern "C" void kernel_launch(void* const* d_in, const int* in_sizes, int n_in,
                              void* d_out, int out_size, void* d_ws, size_t ws_size,
                              hipStream_t stream)
{
  const float* x   = (const float*)d_in[0];
  const int*   src = (const int*)  d_in[1];
  const int*   dst = (const int*)  d_in[2];
  const int*   cu  = (const int*)  d_in[3];
  const int*   cv  = (const int*)  d_in[4];
  const float* cf  = (const float*)d_in[5];
  const float* ws0 = (const float*)d_in[6];
  const float* wn0 = (const float*)d_in[7];
  const float* b0  = (const float*)d_in[8];
  const float* g0  = (const float*)d_in[9];
  const float* be0 = (const float*)d_in[10];
  const float* rm0 = (const float*)d_in[11];
  const float* rv0 = (const float*)d_in[12];
  const float* ws1 = (const float*)d_in[13];
  const float* wn1 = (const float*)d_in[14];
  const float* b1  = (const float*)d_in[15];
  const float* g1  = (const float*)d_in[16];
  const float* be1 = (const float*)d_in[17];
  const float* rm1 = (const float*)d_in[18];
  const float* rv1 = (const float*)d_in[19];
  const float* mw0 = (const float*)d_in[20];
  const float* mb0 = (const float*)d_in[21];
  const float* mw1 = (const float*)d_in[22];
  const float* mb1 = (const float*)d_in[23];
  const float* mw2 = (const float*)d_in[24];
  const float* mb2 = (const float*)d_in[25];

  float* out = (float*)d_out;   // [C] y then [C] softmax

  char* w = (char*)d_ws;
  float* aggn  = (float*)w; w += (size_t)N_NODES * D * 4;
  float* h0    = (float*)w; w += (size_t)N_NODES * D * 4;
  float* h1    = (float*)w; w += (size_t)N_NODES * D * 4;
  int* cnt     = (int*)w;   w += (size_t)N_NODES * 4;
  int* rowptr  = (int*)w;   w += (size_t)(N_NODES + 1) * 4;
  int* cur     = (int*)w;   w += (size_t)N_NODES * 4;
  int* eid     = (int*)w;   w += (size_t)N_EDGES * 4;
  int* bsumI   = (int*)w;   w += 256 * 4;
  float* bmax  = (float*)w; w += 256 * 4;
  float* bsumF = (float*)w; w += 256 * 4;
  float* gred  = (float*)w; w += 2 * 4;

  // split-bf16 weight buffers alias the CSR scratch that is dead after k_fill:
  // cnt (200 KB) holds layer-0 bth|btl (2 x 64 KB); cur (200 KB) holds layer-1.
  unsigned short* bth0 = (unsigned short*)cnt;
  unsigned short* btl0 = bth0 + 128 * 256;
  unsigned short* bth1 = (unsigned short*)cur;
  unsigned short* btl1 = bth1 + 128 * 256;

  hipMemsetAsync(cnt, 0, (size_t)N_NODES * 4, stream);
  hipMemsetAsync(cur, 0, (size_t)N_NODES * 4, stream);

  int SB = (N_NODES + 255) / 256;   // 196
  k_hist <<<(N_EDGES + 255) / 256, 256, 0, stream>>>(dst, cnt, N_EDGES);
  k_scan1<<<SB, 256, 0, stream>>>(cnt, rowptr, bsumI, N_NODES);
  k_scan2<<<1, 256, 0, stream>>>(bsumI, rowptr, SB, N_NODES);
  k_scan3<<<SB, 256, 0, stream>>>(rowptr, bsumI, N_NODES);
  k_fill <<<(N_EDGES + 255) / 256, 256, 0, stream>>>(src, dst, rowptr, cur, eid, N_EDGES);

  // cnt/cur are dead now -> reuse for split weights
  k_cvt_w<<<128, 256, 0, stream>>>(ws0, wn0, bth0, btl0);
  k_cvt_w<<<128, 256, 0, stream>>>(ws1, wn1, bth1, btl1);

  int GB = (N_NODES + 63) / 64;     // 782
  k_agg <<<(N_NODES + 7) / 8, 256, 0, stream>>>(x, rowptr, eid, aggn, N_NODES);
  k_sage_mfma<<<GB, 256, 0, stream>>>(x,  aggn, bth0, btl0, b0, g0, be0, rm0, rv0, h0, N_NODES, 0);
  k_agg <<<(N_NODES + 7) / 8, 256, 0, stream>>>(h0, rowptr, eid, aggn, N_NODES);
  k_sage_mfma<<<GB, 256, 0, stream>>>(h0, aggn, bth1, btl1, b1, g1, be1, rm1, rv1, h1, N_NODES, 1);

  k_mlp <<<(N_CAND + 63) / 64, 256, 0, stream>>>(h1, cu, cv, cf, mw0, mb0, mw1, mb1, mw2, mb2, out, N_CAND);

  k_red1<<<256, 256, 0, stream>>>(out, bmax, bsumF, N_CAND);
  k_red2<<<1, 256, 0, stream>>>(bmax, bsumF, gred, 256);
  k_red3<<<(N_CAND + 255) / 256, 256, 0, stream>>>(out, gred, out + N_CAND, N_CAND);
}

// Round 5
// 339.046 us; speedup vs baseline: 1.4787x; 1.0549x over previous
//
#include <hip/hip_runtime.h>
#include <math.h>

#define N_NODES 50000
#define N_EDGES 800000
#define N_CAND  100000
#define D       128
#define BN_EPS  1e-5f
#define SLOPE   0.01f

typedef __attribute__((ext_vector_type(8))) short bf16x8;
typedef __attribute__((ext_vector_type(4))) float f32x4;

__device__ __forceinline__ float lrelu(float x){ return x >= 0.f ? x : SLOPE * x; }

__device__ __forceinline__ unsigned short f2bf_rn(float f){
  unsigned int u = __float_as_uint(f);
  unsigned int r = u + 0x7FFFu + ((u >> 16) & 1u);
  return (unsigned short)(r >> 16);
}
__device__ __forceinline__ float bf2f(unsigned short h){
  return __uint_as_float(((unsigned int)h) << 16);
}

// pack 2 f32 -> 2 bf16 in one inst ([15:0]=bf16(a), [31:16]=bf16(b))
__device__ __forceinline__ unsigned pk_bf16(float a, float b){
  unsigned r;
  asm("v_cvt_pk_bf16_f32 %0, %1, %2" : "=v"(r) : "v"(a), "v"(b));
  return r;
}
// split pair into hi + lo ( lo = rn(x - hi) -> self-correcting wrt cvt rounding )
__device__ __forceinline__ void split2(float a, float b, unsigned &h, unsigned &l){
  h = pk_bf16(a, b);
  float ra = a - __uint_as_float(h << 16);
  float rb = b - __uint_as_float(h & 0xffff0000u);
  l = pk_bf16(ra, rb);
}
// split a float4-pair (8 consecutive k) into A-fragment hi/lo
__device__ __forceinline__ void split8(const float4 &v0, const float4 &v1, uint4 &h, uint4 &l){
  split2(v0.x, v0.y, h.x, l.x);
  split2(v0.z, v0.w, h.y, l.y);
  split2(v1.x, v1.y, h.z, l.z);
  split2(v1.z, v1.w, h.w, l.w);
}

// ---------------- CSR build ----------------
__global__ __launch_bounds__(256) void k_hist(const int* __restrict__ dst, int* __restrict__ cnt, int E){
  int i = blockIdx.x * 256 + threadIdx.x;
  if (i < E) atomicAdd(&cnt[dst[i]], 1);
}

__global__ __launch_bounds__(256) void k_scan1(const int* __restrict__ cnt, int* __restrict__ rowptr,
                                               int* __restrict__ bsum, int n){
  __shared__ int sd[256];
  int t = threadIdx.x; int i = blockIdx.x * 256 + t;
  int v = (i < n) ? cnt[i] : 0;
  sd[t] = v; __syncthreads();
  for (int off = 1; off < 256; off <<= 1){
    int add = (t >= off) ? sd[t - off] : 0;
    __syncthreads();
    sd[t] += add; __syncthreads();
  }
  if (i < n) rowptr[i] = sd[t] - v;          // exclusive within block
  if (t == 255) bsum[blockIdx.x] = sd[255];  // block total
}

__global__ __launch_bounds__(256) void k_scan2(int* __restrict__ bsum, int* __restrict__ rowptr, int nb, int n){
  __shared__ int sd[256];
  int t = threadIdx.x;
  int v = (t < nb) ? bsum[t] : 0;
  sd[t] = v; __syncthreads();
  for (int off = 1; off < 256; off <<= 1){
    int add = (t >= off) ? sd[t - off] : 0;
    __syncthreads();
    sd[t] += add; __syncthreads();
  }
  if (t < nb) bsum[t] = sd[t] - v;           // exclusive block offsets
  if (t == nb - 1) rowptr[n] = sd[t];        // total = E
}

__global__ __launch_bounds__(256) void k_scan3(int* __restrict__ rowptr, const int* __restrict__ bsum, int n){
  int i = blockIdx.x * 256 + threadIdx.x;
  if (i < n) rowptr[i] += bsum[blockIdx.x];
}

__global__ __launch_bounds__(256) void k_fill(const int* __restrict__ src, const int* __restrict__ dst,
                                              const int* __restrict__ rowptr, int* __restrict__ cur,
                                              int* __restrict__ eid, int E){
  int i = blockIdx.x * 256 + threadIdx.x;
  if (i < E){
    int d = dst[i];
    int p = atomicAdd(&cur[d], 1);
    eid[rowptr[d] + p] = src[i];
  }
}

// ---------------- weight transpose + bf16 hi/lo split (SAGE) ----------------
// Wcat = [WS ; WN] (256 x 128, row-major k x col) ->  BT_h/BT_l [col][k] (128 x 256)
__global__ __launch_bounds__(256) void k_cvt_w(const float* __restrict__ ws, const float* __restrict__ wn,
                                               unsigned short* __restrict__ bth, unsigned short* __restrict__ btl){
  int col = blockIdx.x;       // 0..127
  int k   = threadIdx.x;      // 0..255
  float v = (k < 128) ? ws[k * D + col] : wn[(k - 128) * D + col];
  unsigned short hi = f2bf_rn(v);
  unsigned short lo = f2bf_rn(v - bf2f(hi));
  bth[col * 256 + k] = hi;
  btl[col * 256 + k] = lo;
}

// ---------------- MLP weight transpose + split: w[K x 64] -> T_h/T_l [64][Kpad] ----------------
__global__ __launch_bounds__(256) void k_cvt_mlp(const float* __restrict__ w, int K, int Kpad,
                                                 unsigned short* __restrict__ th, unsigned short* __restrict__ tl){
  int col = blockIdx.x;       // 0..63
  for (int k = threadIdx.x; k < Kpad; k += 256){
    float v = (k < K) ? w[k * 64 + col] : 0.f;
    unsigned short hi = f2bf_rn(v);
    th[col * Kpad + k] = hi;
    tl[col * Kpad + k] = f2bf_rn(v - bf2f(hi));
  }
}

// ---------------- mean aggregation (gather-sum over CSR) ----------------
__global__ __launch_bounds__(256) void k_agg(const float* __restrict__ X, const int* __restrict__ rowptr,
                                             const int* __restrict__ eid, float* __restrict__ AG, int n){
  int g = blockIdx.x * 8 + (threadIdx.x >> 5);   // node, 32 lanes per node
  int l = threadIdx.x & 31;                      // float4 chunk
  if (g >= n) return;
  int e0 = rowptr[g], e1 = rowptr[g + 1];
  float4 acc = make_float4(0.f, 0.f, 0.f, 0.f);
  for (int e = e0; e < e1; ++e){
    int s = eid[e];
    const float4 v = *reinterpret_cast<const float4*>(&X[(size_t)s * D + l * 4]);
    acc.x += v.x; acc.y += v.y; acc.z += v.z; acc.w += v.w;
  }
  float sc = 1.f / fmaxf((float)(e1 - e0), 1.f);
  acc.x *= sc; acc.y *= sc; acc.z *= sc; acc.w *= sc;
  *reinterpret_cast<float4*>(&AG[(size_t)g * D + l * 4]) = acc;
}

// ---------------- SAGE layer via split-bf16 MFMA ----------------
__global__ __launch_bounds__(256) void k_sage_mfma(const float* __restrict__ XS, const float* __restrict__ AG,
    const unsigned short* __restrict__ BTH, const unsigned short* __restrict__ BTL,
    const float* __restrict__ Bb, const float* __restrict__ GM, const float* __restrict__ BT,
    const float* __restrict__ RM, const float* __restrict__ RV,
    float* __restrict__ H, int n, int donan)
{
  __shared__ unsigned short Ah[64 * 40];
  __shared__ unsigned short Al[64 * 40];
  __shared__ unsigned short Bh[128 * 40];
  __shared__ unsigned short Bl[128 * 40];

  int t  = threadIdx.x;
  int l  = t & 63;
  int wv = t >> 6;          // wave 0..3 -> rows wv*16..+15
  int lm = l & 15;          // frag row (A) / col (B,D)
  int lk = l >> 4;          // k-group 0..3
  int node0 = blockIdx.x * 64;

  f32x4 acc[8];
  #pragma unroll
  for (int f = 0; f < 8; ++f) acc[f] = (f32x4){0.f, 0.f, 0.f, 0.f};

  for (int step = 0; step < 8; ++step){
    int k0 = step * 32;                          // global k in [0,256)
    const float* srcA = (step < 4) ? XS : AG;
    int koff = (step < 4) ? k0 : (k0 - 128);

    __syncthreads();
    // ---- stage A: 64 rows x 32 k fp32 -> hi/lo bf16 ----
    #pragma unroll
    for (int i = 0; i < 2; ++i){
      int c   = t + i * 256;
      int row = c >> 3, c4 = c & 7;
      int node = min(node0 + row, n - 1);
      float4 v = *reinterpret_cast<const float4*>(&srcA[(size_t)node * D + koff + c4 * 4]);
      const float* vp = (const float*)&v;
      unsigned short hh[4], ll[4];
      #pragma unroll
      for (int j = 0; j < 4; ++j){
        unsigned short hi = f2bf_rn(vp[j]);
        hh[j] = hi;
        ll[j] = f2bf_rn(vp[j] - bf2f(hi));
      }
      uint2 wh, wl;
      wh.x = (unsigned)hh[0] | ((unsigned)hh[1] << 16);
      wh.y = (unsigned)hh[2] | ((unsigned)hh[3] << 16);
      wl.x = (unsigned)ll[0] | ((unsigned)ll[1] << 16);
      wl.y = (unsigned)ll[2] | ((unsigned)ll[3] << 16);
      *reinterpret_cast<uint2*>(&Ah[row * 40 + c4 * 4]) = wh;
      *reinterpret_cast<uint2*>(&Al[row * 40 + c4 * 4]) = wl;
    }
    // ---- stage B: 128 cols x 32 k bf16 hi+lo ----
    #pragma unroll
    for (int i = 0; i < 2; ++i){
      int c   = t + i * 256;
      int col = c >> 2, q = c & 3;
      *reinterpret_cast<uint4*>(&Bh[col * 40 + q * 8]) =
          *reinterpret_cast<const uint4*>(&BTH[col * 256 + k0 + q * 8]);
      *reinterpret_cast<uint4*>(&Bl[col * 40 + q * 8]) =
          *reinterpret_cast<const uint4*>(&BTL[col * 256 + k0 + q * 8]);
    }
    __syncthreads();

    // ---- MFMA: 8 col-frags x 3 split terms ----
    bf16x8 afh = *reinterpret_cast<const bf16x8*>(&Ah[(wv * 16 + lm) * 40 + lk * 8]);
    bf16x8 afl = *reinterpret_cast<const bf16x8*>(&Al[(wv * 16 + lm) * 40 + lk * 8]);
    #pragma unroll
    for (int f = 0; f < 8; ++f){
      bf16x8 bfh = *reinterpret_cast<const bf16x8*>(&Bh[(f * 16 + lm) * 40 + lk * 8]);
      bf16x8 bfl = *reinterpret_cast<const bf16x8*>(&Bl[(f * 16 + lm) * 40 + lk * 8]);
      acc[f] = __builtin_amdgcn_mfma_f32_16x16x32_bf16(afh, bfh, acc[f], 0, 0, 0);
      acc[f] = __builtin_amdgcn_mfma_f32_16x16x32_bf16(afl, bfh, acc[f], 0, 0, 0);
      acc[f] = __builtin_amdgcn_mfma_f32_16x16x32_bf16(afh, bfl, acc[f], 0, 0, 0);
    }
  }

  // ---- epilogue: BN + leaky relu (+ nan_to_num layer 2) ----
  #pragma unroll
  for (int f = 0; f < 8; ++f){
    int col = f * 16 + lm;
    float s  = GM[col] * rsqrtf(RV[col] + BN_EPS);
    float cj = (Bb[col] - RM[col]) * s + BT[col];
    #pragma unroll
    for (int r = 0; r < 4; ++r){
      int node = node0 + wv * 16 + lk * 4 + r;
      if (node < n){
        float v = lrelu(acc[f][r] * s + cj);
        if (donan && (v != v)) v = 1e-14f;
        H[(size_t)node * D + col] = v;
      }
    }
  }
}

// ---------------- candidate MLP via split-bf16 MFMA ----------------
// [h_u | h_v | feat] (257) -> 64 -> 64 -> 1.
// Block = 256 thr (4 waves) x 128 candidates; wave owns 32 cands (2 M-frags).
// L1: A-frags gathered DIRECTLY from global H (lane reads its row's 32B
// k-slice), split hi/lo in-register via v_cvt_pk_bf16_f32; B-frags from
// pre-split transposed weights W0T[col][Kpad=264]. Feat col + bias in epilogue.
// L1->L2 transpose through per-wave LDS tile (row stride 144B = 9*16B ->
// b128 A-frag reads 2-way bank alias = free; wave-local, no barrier).
// L3: per-lane partials + 16-lane shfl_xor reduce.
// Fragment conventions identical to k_sage_mfma (proven): A row=l&15,
// k=8*(l>>4)+j; B col=l&15; D col=l&15, row=(l>>4)*4+reg.
__global__ __launch_bounds__(256) void k_mlp_mfma(const float* __restrict__ H,
    const int* __restrict__ cu, const int* __restrict__ cv, const float* __restrict__ cf,
    const unsigned short* __restrict__ W0H, const unsigned short* __restrict__ W0L,
    const float* __restrict__ mw0, const float* __restrict__ mb0,
    const unsigned short* __restrict__ W1H, const unsigned short* __restrict__ W1L,
    const float* __restrict__ mb1, const float* __restrict__ mw2, const float* __restrict__ mb2,
    float* __restrict__ y, int C)
{
  __shared__ unsigned short zh[4][32 * 72];   // per-wave z tile, hi (rows 144B)
  __shared__ unsigned short zl[4][32 * 72];   // per-wave z tile, lo

  int t = threadIdx.x;
  int wv = t >> 6, l = t & 63, lm = l & 15, lk = l >> 4;
  int candbase = blockIdx.x * 128 + wv * 32;

  // node ids for my two A-rows (m-frag 0: rows 0..15, m-frag 1: rows 16..31)
  int c0 = min(candbase + lm,      C - 1);
  int c1 = min(candbase + 16 + lm, C - 1);
  int nu0 = cu[c0], nv0 = cv[c0];
  int nu1 = cu[c1], nv1 = cv[c1];

  // ---- layer 1: K = 256 via MFMA ----
  f32x4 acc[2][4];
  #pragma unroll
  for (int m = 0; m < 2; ++m)
    #pragma unroll
    for (int f = 0; f < 4; ++f) acc[m][f] = (f32x4){0.f, 0.f, 0.f, 0.f};

  #pragma unroll
  for (int s = 0; s < 8; ++s){
    int n0 = (s < 4) ? nu0 : nv0;
    int n1 = (s < 4) ? nu1 : nv1;
    int koff = (s & 3) * 32 + lk * 8;
    const float4* p0 = reinterpret_cast<const float4*>(&H[(size_t)n0 * D + koff]);
    const float4* p1 = reinterpret_cast<const float4*>(&H[(size_t)n1 * D + koff]);
    float4 a00 = p0[0], a01 = p0[1];
    float4 a10 = p1[0], a11 = p1[1];
    uint4 h0, l0, h1, l1;
    split8(a00, a01, h0, l0);
    split8(a10, a11, h1, l1);
    bf16x8 afh0 = *reinterpret_cast<bf16x8*>(&h0);
    bf16x8 afl0 = *reinterpret_cast<bf16x8*>(&l0);
    bf16x8 afh1 = *reinterpret_cast<bf16x8*>(&h1);
    bf16x8 afl1 = *reinterpret_cast<bf16x8*>(&l1);

    int k0 = s * 32 + lk * 8;
    #pragma unroll
    for (int f = 0; f < 4; ++f){
      int col = f * 16 + lm;
      bf16x8 bh = *reinterpret_cast<const bf16x8*>(&W0H[(size_t)col * 264 + k0]);
      bf16x8 bl = *reinterpret_cast<const bf16x8*>(&W0L[(size_t)col * 264 + k0]);
      acc[0][f] = __builtin_amdgcn_mfma_f32_16x16x32_bf16(afh0, bh, acc[0][f], 0, 0, 0);
      acc[0][f] = __builtin_amdgcn_mfma_f32_16x16x32_bf16(afl0, bh, acc[0][f], 0, 0, 0);
      acc[0][f] = __builtin_amdgcn_mfma_f32_16x16x32_bf16(afh0, bl, acc[0][f], 0, 0, 0);
      acc[1][f] = __builtin_amdgcn_mfma_f32_16x16x32_bf16(afh1, bh, acc[1][f], 0, 0, 0);
      acc[1][f] = __builtin_amdgcn_mfma_f32_16x16x32_bf16(afl1, bh, acc[1][f], 0, 0, 0);
      acc[1][f] = __builtin_amdgcn_mfma_f32_16x16x32_bf16(afh1, bl, acc[1][f], 0, 0, 0);
    }
  }

  // ---- L1 epilogue: bias + feat term + lrelu, write z hi/lo to LDS ----
  float cfv[2][4];
  #pragma unroll
  for (int m = 0; m < 2; ++m)
    #pragma unroll
    for (int r = 0; r < 4; ++r)
      cfv[m][r] = cf[min(candbase + m * 16 + lk * 4 + r, C - 1)];

  #pragma unroll
  for (int f = 0; f < 4; ++f){
    int col = f * 16 + lm;
    float b0v = mb0[col];
    float wfv = mw0[256 * 64 + col];
    #pragma unroll
    for (int m = 0; m < 2; ++m){
      #pragma unroll
      for (int r = 0; r < 4; ++r){
        int cl = m * 16 + lk * 4 + r;
        float z = lrelu(acc[m][f][r] + b0v + cfv[m][r] * wfv);
        unsigned short h16 = f2bf_rn(z);
        zh[wv][cl * 72 + col] = h16;
        zl[wv][cl * 72 + col] = f2bf_rn(z - bf2f(h16));
      }
    }
  }
  // wave-local LDS: hardware lgkmcnt ordering covers write->read, no barrier

  // ---- layer 2: K = 64 via MFMA ----
  f32x4 a2[2][4];
  #pragma unroll
  for (int m = 0; m < 2; ++m)
    #pragma unroll
    for (int f = 0; f < 4; ++f) a2[m][f] = (f32x4){0.f, 0.f, 0.f, 0.f};

  #pragma unroll
  for (int s2 = 0; s2 < 2; ++s2){
    int kk = s2 * 32 + lk * 8;
    bf16x8 azh0 = *reinterpret_cast<const bf16x8*>(&zh[wv][(0 * 16 + lm) * 72 + kk]);
    bf16x8 azl0 = *reinterpret_cast<const bf16x8*>(&zl[wv][(0 * 16 + lm) * 72 + kk]);
    bf16x8 azh1 = *reinterpret_cast<const bf16x8*>(&zh[wv][(1 * 16 + lm) * 72 + kk]);
    bf16x8 azl1 = *reinterpret_cast<const bf16x8*>(&zl[wv][(1 * 16 + lm) * 72 + kk]);
    #pragma unroll
    for (int f = 0; f < 4; ++f){
      int col = f * 16 + lm;
      bf16x8 bh = *reinterpret_cast<const bf16x8*>(&W1H[(size_t)col * 64 + kk]);
      bf16x8 bl = *reinterpret_cast<const bf16x8*>(&W1L[(size_t)col * 64 + kk]);
      a2[0][f] = __builtin_amdgcn_mfma_f32_16x16x32_bf16(azh0, bh, a2[0][f], 0, 0, 0);
      a2[0][f] = __builtin_amdgcn_mfma_f32_16x16x32_bf16(azl0, bh, a2[0][f], 0, 0, 0);
      a2[0][f] = __builtin_amdgcn_mfma_f32_16x16x32_bf16(azh0, bl, a2[0][f], 0, 0, 0);
      a2[1][f] = __builtin_amdgcn_mfma_f32_16x16x32_bf16(azh1, bh, a2[1][f], 0, 0, 0);
      a2[1][f] = __builtin_amdgcn_mfma_f32_16x16x32_bf16(azl1, bh, a2[1][f], 0, 0, 0);
      a2[1][f] = __builtin_amdgcn_mfma_f32_16x16x32_bf16(azh1, bl, a2[1][f], 0, 0, 0);
    }
  }

  // ---- layer 3: 64 -> 1 : per-lane partial + 16-lane xor reduce ----
  float p00 = 0.f, p01 = 0.f, p02 = 0.f, p03 = 0.f;
  float p10 = 0.f, p11 = 0.f, p12 = 0.f, p13 = 0.f;
  #pragma unroll
  for (int f = 0; f < 4; ++f){
    int col = f * 16 + lm;
    float b1v = mb1[col];
    float w2v = mw2[col];
    p00 = fmaf(lrelu(a2[0][f][0] + b1v), w2v, p00);
    p01 = fmaf(lrelu(a2[0][f][1] + b1v), w2v, p01);
    p02 = fmaf(lrelu(a2[0][f][2] + b1v), w2v, p02);
    p03 = fmaf(lrelu(a2[0][f][3] + b1v), w2v, p03);
    p10 = fmaf(lrelu(a2[1][f][0] + b1v), w2v, p10);
    p11 = fmaf(lrelu(a2[1][f][1] + b1v), w2v, p11);
    p12 = fmaf(lrelu(a2[1][f][2] + b1v), w2v, p12);
    p13 = fmaf(lrelu(a2[1][f][3] + b1v), w2v, p13);
  }
  #pragma unroll
  for (int off = 1; off < 16; off <<= 1){
    p00 += __shfl_xor(p00, off); p01 += __shfl_xor(p01, off);
    p02 += __shfl_xor(p02, off); p03 += __shfl_xor(p03, off);
    p10 += __shfl_xor(p10, off); p11 += __shfl_xor(p11, off);
    p12 += __shfl_xor(p12, off); p13 += __shfl_xor(p13, off);
  }
  if (lm == 0){
    float b2 = mb2[0];
    int base0 = candbase + lk * 4;
    int base1 = candbase + 16 + lk * 4;
    if (base0 + 0 < C) y[base0 + 0] = p00 + b2;
    if (base0 + 1 < C) y[base0 + 1] = p01 + b2;
    if (base0 + 2 < C) y[base0 + 2] = p02 + b2;
    if (base0 + 3 < C) y[base0 + 3] = p03 + b2;
    if (base1 + 0 < C) y[base1 + 0] = p10 + b2;
    if (base1 + 1 < C) y[base1 + 1] = p11 + b2;
    if (base1 + 2 < C) y[base1 + 2] = p12 + b2;
    if (base1 + 3 < C) y[base1 + 3] = p13 + b2;
  }
}

// ---------------- softmax over C logits ----------------
__global__ __launch_bounds__(256) void k_red1(const float* __restrict__ y,
                                              float* __restrict__ bmax, float* __restrict__ bsum, int C){
  __shared__ float sm[4];
  __shared__ float ss[4];
  int t = threadIdx.x;
  float m = -3.4e38f;
  for (int i = blockIdx.x * 256 + t; i < C; i += gridDim.x * 256) m = fmaxf(m, y[i]);
  for (int o = 32; o; o >>= 1) m = fmaxf(m, __shfl_xor(m, o));
  if ((t & 63) == 0) sm[t >> 6] = m;
  __syncthreads();
  float bm = fmaxf(fmaxf(sm[0], sm[1]), fmaxf(sm[2], sm[3]));
  float s = 0.f;
  for (int i = blockIdx.x * 256 + t; i < C; i += gridDim.x * 256) s += expf(y[i] - bm);
  for (int o = 32; o; o >>= 1) s += __shfl_xor(s, o);
  if ((t & 63) == 0) ss[t >> 6] = s;
  __syncthreads();
  if (t == 0){ bmax[blockIdx.x] = bm; bsum[blockIdx.x] = ss[0] + ss[1] + ss[2] + ss[3]; }
}

__global__ __launch_bounds__(256) void k_red2(const float* __restrict__ bmax, const float* __restrict__ bsum,
                                              float* __restrict__ g, int nb){
  __shared__ float sm[4];
  __shared__ float ss[4];
  int t = threadIdx.x;
  float m0 = (t < nb) ? bmax[t] : -3.4e38f;
  float m = m0;
  for (int o = 32; o; o >>= 1) m = fmaxf(m, __shfl_xor(m, o));
  if ((t & 63) == 0) sm[t >> 6] = m;
  __syncthreads();
  float gm = fmaxf(fmaxf(sm[0], sm[1]), fmaxf(sm[2], sm[3]));
  float s = (t < nb) ? bsum[t] * expf(m0 - gm) : 0.f;
  for (int o = 32; o; o >>= 1) s += __shfl_xor(s, o);
  if ((t & 63) == 0) ss[t >> 6] = s;
  __syncthreads();
  if (t == 0){ g[0] = gm; g[1] = 1.f / (ss[0] + ss[1] + ss[2] + ss[3]); }
}

__global__ __launch_bounds__(256) void k_red3(const float* __restrict__ y, const float* __restrict__ g,
                                              float* __restrict__ out, int C){
  int i = blockIdx.x * 256 + threadIdx.x;
  if (i < C) out[i] = expf(y[i] - g[0]) * g[1];
}

extern "C" void kernel_launch(void* const* d_in, const int* in_sizes, int n_in,
                              void* d_out, int out_size, void* d_ws, size_t ws_size,
                              hipStream_t stream)
{
  const float* x   = (const float*)d_in[0];
  const int*   src = (const int*)  d_in[1];
  const int*   dst = (const int*)  d_in[2];
  const int*   cu  = (const int*)  d_in[3];
  const int*   cv  = (const int*)  d_in[4];
  const float* cf  = (const float*)d_in[5];
  const float* ws0 = (const float*)d_in[6];
  const float* wn0 = (const float*)d_in[7];
  const float* b0  = (const float*)d_in[8];
  const float* g0  = (const float*)d_in[9];
  const float* be0 = (const float*)d_in[10];
  const float* rm0 = (const float*)d_in[11];
  const float* rv0 = (const float*)d_in[12];
  const float* ws1 = (const float*)d_in[13];
  const float* wn1 = (const float*)d_in[14];
  const float* b1  = (const float*)d_in[15];
  const float* g1  = (const float*)d_in[16];
  const float* be1 = (const float*)d_in[17];
  const float* rm1 = (const float*)d_in[18];
  const float* rv1 = (const float*)d_in[19];
  const float* mw0 = (const float*)d_in[20];
  const float* mb0 = (const float*)d_in[21];
  const float* mw1 = (const float*)d_in[22];
  const float* mb1 = (const float*)d_in[23];
  const float* mw2 = (const float*)d_in[24];
  const float* mb2 = (const float*)d_in[25];

  float* out = (float*)d_out;   // [C] y then [C] softmax

  char* w = (char*)d_ws;
  float* aggn  = (float*)w; w += (size_t)N_NODES * D * 4;
  float* h0    = (float*)w; w += (size_t)N_NODES * D * 4;
  float* h1    = (float*)w; w += (size_t)N_NODES * D * 4;
  int* cnt     = (int*)w;   w += (size_t)N_NODES * 4;
  int* rowptr  = (int*)w;   w += (size_t)(N_NODES + 1) * 4;
  int* cur     = (int*)w;   w += (size_t)N_NODES * 4;
  int* eid     = (int*)w;   w += (size_t)N_EDGES * 4;
  int* bsumI   = (int*)w;   w += 256 * 4;
  float* bmax  = (float*)w; w += 256 * 4;
  float* bsumF = (float*)w; w += 256 * 4;
  float* gred  = (float*)w; w += 2 * 4;
  // split MLP weights (transposed): w0 [64][264] hi/lo, w1 [64][64] hi/lo
  unsigned short* w0th = (unsigned short*)w; w += (size_t)64 * 264 * 2;
  unsigned short* w0tl = (unsigned short*)w; w += (size_t)64 * 264 * 2;
  unsigned short* w1th = (unsigned short*)w; w += (size_t)64 * 64 * 2;
  unsigned short* w1tl = (unsigned short*)w; w += (size_t)64 * 64 * 2;

  // split-bf16 SAGE weight buffers alias the CSR scratch dead after k_fill:
  unsigned short* bth0 = (unsigned short*)cnt;
  unsigned short* btl0 = bth0 + 128 * 256;
  unsigned short* bth1 = (unsigned short*)cur;
  unsigned short* btl1 = bth1 + 128 * 256;

  hipMemsetAsync(cnt, 0, (size_t)N_NODES * 4, stream);
  hipMemsetAsync(cur, 0, (size_t)N_NODES * 4, stream);

  int SB = (N_NODES + 255) / 256;   // 196
  k_hist <<<(N_EDGES + 255) / 256, 256, 0, stream>>>(dst, cnt, N_EDGES);
  k_scan1<<<SB, 256, 0, stream>>>(cnt, rowptr, bsumI, N_NODES);
  k_scan2<<<1, 256, 0, stream>>>(bsumI, rowptr, SB, N_NODES);
  k_scan3<<<SB, 256, 0, stream>>>(rowptr, bsumI, N_NODES);
  k_fill <<<(N_EDGES + 255) / 256, 256, 0, stream>>>(src, dst, rowptr, cur, eid, N_EDGES);

  // cnt/cur are dead now -> reuse for SAGE split weights
  k_cvt_w<<<128, 256, 0, stream>>>(ws0, wn0, bth0, btl0);
  k_cvt_w<<<128, 256, 0, stream>>>(ws1, wn1, bth1, btl1);
  k_cvt_mlp<<<64, 256, 0, stream>>>(mw0, 257, 264, w0th, w0tl);
  k_cvt_mlp<<<64, 256, 0, stream>>>(mw1, 64, 64, w1th, w1tl);

  int GB = (N_NODES + 63) / 64;     // 782
  k_agg <<<(N_NODES + 7) / 8, 256, 0, stream>>>(x, rowptr, eid, aggn, N_NODES);
  k_sage_mfma<<<GB, 256, 0, stream>>>(x,  aggn, bth0, btl0, b0, g0, be0, rm0, rv0, h0, N_NODES, 0);
  k_agg <<<(N_NODES + 7) / 8, 256, 0, stream>>>(h0, rowptr, eid, aggn, N_NODES);
  k_sage_mfma<<<GB, 256, 0, stream>>>(h0, aggn, bth1, btl1, b1, g1, be1, rm1, rv1, h1, N_NODES, 1);

  k_mlp_mfma<<<(N_CAND + 127) / 128, 256, 0, stream>>>(h1, cu, cv, cf,
      w0th, w0tl, mw0, mb0, w1th, w1tl, mb1, mw2, mb2, out, N_CAND);

  k_red1<<<256, 256, 0, stream>>>(out, bmax, bsumF, N_CAND);
  k_red2<<<1, 256, 0, stream>>>(bmax, bsumF, gred, 256);
  k_red3<<<(N_CAND + 255) / 256, 256, 0, stream>>>(out, gred, out + N_CAND, N_CAND);
}

// Round 6
// 296.249 us; speedup vs baseline: 1.6923x; 1.1445x over previous
//
#include <hip/hip_runtime.h>
#include <math.h>

#define N_NODES 50000
#define N_EDGES 800000
#define N_CAND  100000
#define D       128
#define BN_EPS  1e-5f
#define SLOPE   0.01f

typedef __attribute__((ext_vector_type(8))) short bf16x8;
typedef __attribute__((ext_vector_type(4))) float f32x4;

__device__ __forceinline__ float lrelu(float x){ return x >= 0.f ? x : SLOPE * x; }

__device__ __forceinline__ unsigned short f2bf_rn(float f){
  unsigned int u = __float_as_uint(f);
  unsigned int r = u + 0x7FFFu + ((u >> 16) & 1u);
  return (unsigned short)(r >> 16);
}
__device__ __forceinline__ float bf2f(unsigned short h){
  return __uint_as_float(((unsigned int)h) << 16);
}
__device__ __forceinline__ float4 bf4f(ushort4 u){
  return make_float4(__uint_as_float((unsigned)u.x << 16),
                     __uint_as_float((unsigned)u.y << 16),
                     __uint_as_float((unsigned)u.z << 16),
                     __uint_as_float((unsigned)u.w << 16));
}

// pack 2 f32 -> 2 bf16 in one inst ([15:0]=bf16(a), [31:16]=bf16(b))
__device__ __forceinline__ unsigned pk_bf16(float a, float b){
  unsigned r;
  asm("v_cvt_pk_bf16_f32 %0, %1, %2" : "=v"(r) : "v"(a), "v"(b));
  return r;
}
// split pair into hi + lo ( lo = rn(x - hi) -> self-correcting wrt cvt rounding )
__device__ __forceinline__ void split2(float a, float b, unsigned &h, unsigned &l){
  h = pk_bf16(a, b);
  float ra = a - __uint_as_float(h << 16);
  float rb = b - __uint_as_float(h & 0xffff0000u);
  l = pk_bf16(ra, rb);
}
// split a float4-pair (8 consecutive k) into A-fragment hi/lo
__device__ __forceinline__ void split8(const float4 &v0, const float4 &v1, uint4 &h, uint4 &l){
  split2(v0.x, v0.y, h.x, l.x);
  split2(v0.z, v0.w, h.y, l.y);
  split2(v1.x, v1.y, h.z, l.z);
  split2(v1.z, v1.w, h.w, l.w);
}

// ---------------- CSR build ----------------
__global__ __launch_bounds__(256) void k_hist(const int* __restrict__ dst, int* __restrict__ cnt, int E){
  int i = blockIdx.x * 256 + threadIdx.x;
  if (i < E) atomicAdd(&cnt[dst[i]], 1);
}

__global__ __launch_bounds__(256) void k_scan1(const int* __restrict__ cnt, int* __restrict__ rowptr,
                                               int* __restrict__ bsum, int n){
  __shared__ int sd[256];
  int t = threadIdx.x; int i = blockIdx.x * 256 + t;
  int v = (i < n) ? cnt[i] : 0;
  sd[t] = v; __syncthreads();
  for (int off = 1; off < 256; off <<= 1){
    int add = (t >= off) ? sd[t - off] : 0;
    __syncthreads();
    sd[t] += add; __syncthreads();
  }
  if (i < n) rowptr[i] = sd[t] - v;          // exclusive within block
  if (t == 255) bsum[blockIdx.x] = sd[255];  // block total
}

__global__ __launch_bounds__(256) void k_scan2(int* __restrict__ bsum, int* __restrict__ rowptr, int nb, int n){
  __shared__ int sd[256];
  int t = threadIdx.x;
  int v = (t < nb) ? bsum[t] : 0;
  sd[t] = v; __syncthreads();
  for (int off = 1; off < 256; off <<= 1){
    int add = (t >= off) ? sd[t - off] : 0;
    __syncthreads();
    sd[t] += add; __syncthreads();
  }
  if (t < nb) bsum[t] = sd[t] - v;           // exclusive block offsets
  if (t == nb - 1) rowptr[n] = sd[t];        // total = E
}

__global__ __launch_bounds__(256) void k_scan3(int* __restrict__ rowptr, const int* __restrict__ bsum, int n){
  int i = blockIdx.x * 256 + threadIdx.x;
  if (i < n) rowptr[i] += bsum[blockIdx.x];
}

__global__ __launch_bounds__(256) void k_fill(const int* __restrict__ src, const int* __restrict__ dst,
                                              const int* __restrict__ rowptr, int* __restrict__ cur,
                                              int* __restrict__ eid, int E){
  int i = blockIdx.x * 256 + threadIdx.x;
  if (i < E){
    int d = dst[i];
    int p = atomicAdd(&cur[d], 1);
    eid[rowptr[d] + p] = src[i];
  }
}

// ---------------- weight transpose + bf16 hi/lo split (SAGE) ----------------
__global__ __launch_bounds__(256) void k_cvt_w(const float* __restrict__ ws, const float* __restrict__ wn,
                                               unsigned short* __restrict__ bth, unsigned short* __restrict__ btl){
  int col = blockIdx.x;       // 0..127
  int k   = threadIdx.x;      // 0..255
  float v = (k < 128) ? ws[k * D + col] : wn[(k - 128) * D + col];
  unsigned short hi = f2bf_rn(v);
  unsigned short lo = f2bf_rn(v - bf2f(hi));
  bth[col * 256 + k] = hi;
  btl[col * 256 + k] = lo;
}

// ---------------- MLP weight transpose + split: w[K x 64] -> T_h/T_l [64][Kpad] ----------------
__global__ __launch_bounds__(256) void k_cvt_mlp(const float* __restrict__ w, int K, int Kpad,
                                                 unsigned short* __restrict__ th, unsigned short* __restrict__ tl){
  int col = blockIdx.x;       // 0..63
  for (int k = threadIdx.x; k < Kpad; k += 256){
    float v = (k < K) ? w[k * 64 + col] : 0.f;
    unsigned short hi = f2bf_rn(v);
    th[col * Kpad + k] = hi;
    tl[col * Kpad + k] = f2bf_rn(v - bf2f(hi));
  }
}

// ---------------- x -> bf16 plane ----------------
__global__ __launch_bounds__(256) void k_cvt_x(const float* __restrict__ X, unsigned short* __restrict__ XB, int nel4){
  int i = blockIdx.x * 256 + threadIdx.x;
  if (i < nel4){
    float4 v = *reinterpret_cast<const float4*>(&X[(size_t)i * 4]);
    ushort4 u;
    u.x = f2bf_rn(v.x); u.y = f2bf_rn(v.y); u.z = f2bf_rn(v.z); u.w = f2bf_rn(v.w);
    *reinterpret_cast<ushort4*>(&XB[(size_t)i * 4]) = u;
  }
}

// ---------------- mean aggregation: bf16 gather (halved traffic), fp32 accumulate ----------------
// 32 lanes per node, lane reads its 8B (4 bf16) slice of each neighbor row.
// Edge loop unrolled x2 with independent accumulators for memory-level parallelism.
__global__ __launch_bounds__(256) void k_agg_bf(const unsigned short* __restrict__ XB,
                                                const int* __restrict__ rowptr, const int* __restrict__ eid,
                                                float* __restrict__ AG, int n){
  int g = blockIdx.x * 8 + (threadIdx.x >> 5);   // node
  int l = threadIdx.x & 31;                      // 4-bf16 chunk
  if (g >= n) return;
  int e0 = rowptr[g], e1 = rowptr[g + 1];
  float4 a0 = make_float4(0.f,0.f,0.f,0.f);
  float4 a1 = make_float4(0.f,0.f,0.f,0.f);
  int e = e0;
  for (; e + 2 <= e1; e += 2){
    int s0 = eid[e], s1 = eid[e + 1];
    ushort4 u0 = *reinterpret_cast<const ushort4*>(&XB[(size_t)s0 * D + l * 4]);
    ushort4 u1 = *reinterpret_cast<const ushort4*>(&XB[(size_t)s1 * D + l * 4]);
    float4 f0 = bf4f(u0), f1 = bf4f(u1);
    a0.x += f0.x; a0.y += f0.y; a0.z += f0.z; a0.w += f0.w;
    a1.x += f1.x; a1.y += f1.y; a1.z += f1.z; a1.w += f1.w;
  }
  if (e < e1){
    int s0 = eid[e];
    ushort4 u0 = *reinterpret_cast<const ushort4*>(&XB[(size_t)s0 * D + l * 4]);
    float4 f0 = bf4f(u0);
    a0.x += f0.x; a0.y += f0.y; a0.z += f0.z; a0.w += f0.w;
  }
  float sc = 1.f / fmaxf((float)(e1 - e0), 1.f);
  float4 o;
  o.x = (a0.x + a1.x) * sc; o.y = (a0.y + a1.y) * sc;
  o.z = (a0.z + a1.z) * sc; o.w = (a0.w + a1.w) * sc;
  *reinterpret_cast<float4*>(&AG[(size_t)g * D + l * 4]) = o;
}

// ---------------- SAGE layer via split-bf16 MFMA ----------------
// H = lrelu(BN([X | AG] @ [WS;WN] + b)); optional extra bf16 output plane HB
// (feeds next layer's bf16 aggregation gather).
__global__ __launch_bounds__(256) void k_sage_mfma(const float* __restrict__ XS, const float* __restrict__ AG,
    const unsigned short* __restrict__ BTH, const unsigned short* __restrict__ BTL,
    const float* __restrict__ Bb, const float* __restrict__ GM, const float* __restrict__ BT,
    const float* __restrict__ RM, const float* __restrict__ RV,
    float* __restrict__ H, unsigned short* __restrict__ HB, int n, int donan)
{
  __shared__ unsigned short Ah[64 * 40];
  __shared__ unsigned short Al[64 * 40];
  __shared__ unsigned short Bh[128 * 40];
  __shared__ unsigned short Bl[128 * 40];

  int t  = threadIdx.x;
  int l  = t & 63;
  int wv = t >> 6;          // wave 0..3 -> rows wv*16..+15
  int lm = l & 15;          // frag row (A) / col (B,D)
  int lk = l >> 4;          // k-group 0..3
  int node0 = blockIdx.x * 64;

  f32x4 acc[8];
  #pragma unroll
  for (int f = 0; f < 8; ++f) acc[f] = (f32x4){0.f, 0.f, 0.f, 0.f};

  for (int step = 0; step < 8; ++step){
    int k0 = step * 32;                          // global k in [0,256)
    const float* srcA = (step < 4) ? XS : AG;
    int koff = (step < 4) ? k0 : (k0 - 128);

    __syncthreads();
    // ---- stage A: 64 rows x 32 k fp32 -> hi/lo bf16 ----
    #pragma unroll
    for (int i = 0; i < 2; ++i){
      int c   = t + i * 256;
      int row = c >> 3, c4 = c & 7;
      int node = min(node0 + row, n - 1);
      float4 v = *reinterpret_cast<const float4*>(&srcA[(size_t)node * D + koff + c4 * 4]);
      const float* vp = (const float*)&v;
      unsigned short hh[4], ll[4];
      #pragma unroll
      for (int j = 0; j < 4; ++j){
        unsigned short hi = f2bf_rn(vp[j]);
        hh[j] = hi;
        ll[j] = f2bf_rn(vp[j] - bf2f(hi));
      }
      uint2 wh, wl;
      wh.x = (unsigned)hh[0] | ((unsigned)hh[1] << 16);
      wh.y = (unsigned)hh[2] | ((unsigned)hh[3] << 16);
      wl.x = (unsigned)ll[0] | ((unsigned)ll[1] << 16);
      wl.y = (unsigned)ll[2] | ((unsigned)ll[3] << 16);
      *reinterpret_cast<uint2*>(&Ah[row * 40 + c4 * 4]) = wh;
      *reinterpret_cast<uint2*>(&Al[row * 40 + c4 * 4]) = wl;
    }
    // ---- stage B: 128 cols x 32 k bf16 hi+lo ----
    #pragma unroll
    for (int i = 0; i < 2; ++i){
      int c   = t + i * 256;
      int col = c >> 2, q = c & 3;
      *reinterpret_cast<uint4*>(&Bh[col * 40 + q * 8]) =
          *reinterpret_cast<const uint4*>(&BTH[col * 256 + k0 + q * 8]);
      *reinterpret_cast<uint4*>(&Bl[col * 40 + q * 8]) =
          *reinterpret_cast<const uint4*>(&BTL[col * 256 + k0 + q * 8]);
    }
    __syncthreads();

    // ---- MFMA: 8 col-frags x 3 split terms ----
    bf16x8 afh = *reinterpret_cast<const bf16x8*>(&Ah[(wv * 16 + lm) * 40 + lk * 8]);
    bf16x8 afl = *reinterpret_cast<const bf16x8*>(&Al[(wv * 16 + lm) * 40 + lk * 8]);
    #pragma unroll
    for (int f = 0; f < 8; ++f){
      bf16x8 bfh = *reinterpret_cast<const bf16x8*>(&Bh[(f * 16 + lm) * 40 + lk * 8]);
      bf16x8 bfl = *reinterpret_cast<const bf16x8*>(&Bl[(f * 16 + lm) * 40 + lk * 8]);
      acc[f] = __builtin_amdgcn_mfma_f32_16x16x32_bf16(afh, bfh, acc[f], 0, 0, 0);
      acc[f] = __builtin_amdgcn_mfma_f32_16x16x32_bf16(afl, bfh, acc[f], 0, 0, 0);
      acc[f] = __builtin_amdgcn_mfma_f32_16x16x32_bf16(afh, bfl, acc[f], 0, 0, 0);
    }
  }

  // ---- epilogue: BN + leaky relu (+ nan_to_num layer 2) ----
  #pragma unroll
  for (int f = 0; f < 8; ++f){
    int col = f * 16 + lm;
    float s  = GM[col] * rsqrtf(RV[col] + BN_EPS);
    float cj = (Bb[col] - RM[col]) * s + BT[col];
    #pragma unroll
    for (int r = 0; r < 4; ++r){
      int node = node0 + wv * 16 + lk * 4 + r;
      if (node < n){
        float v = lrelu(acc[f][r] * s + cj);
        if (donan && (v != v)) v = 1e-14f;
        H[(size_t)node * D + col] = v;
        if (HB) HB[(size_t)node * D + col] = f2bf_rn(v);
      }
    }
  }
}

// ---------------- candidate MLP via split-bf16 MFMA ----------------
__global__ __launch_bounds__(256) void k_mlp_mfma(const float* __restrict__ H,
    const int* __restrict__ cu, const int* __restrict__ cv, const float* __restrict__ cf,
    const unsigned short* __restrict__ W0H, const unsigned short* __restrict__ W0L,
    const float* __restrict__ mw0, const float* __restrict__ mb0,
    const unsigned short* __restrict__ W1H, const unsigned short* __restrict__ W1L,
    const float* __restrict__ mb1, const float* __restrict__ mw2, const float* __restrict__ mb2,
    float* __restrict__ y, int C)
{
  __shared__ unsigned short zh[4][32 * 72];   // per-wave z tile, hi (rows 144B)
  __shared__ unsigned short zl[4][32 * 72];   // per-wave z tile, lo

  int t = threadIdx.x;
  int wv = t >> 6, l = t & 63, lm = l & 15, lk = l >> 4;
  int candbase = blockIdx.x * 128 + wv * 32;

  int c0 = min(candbase + lm,      C - 1);
  int c1 = min(candbase + 16 + lm, C - 1);
  int nu0 = cu[c0], nv0 = cv[c0];
  int nu1 = cu[c1], nv1 = cv[c1];

  // ---- layer 1: K = 256 via MFMA ----
  f32x4 acc[2][4];
  #pragma unroll
  for (int m = 0; m < 2; ++m)
    #pragma unroll
    for (int f = 0; f < 4; ++f) acc[m][f] = (f32x4){0.f, 0.f, 0.f, 0.f};

  #pragma unroll
  for (int s = 0; s < 8; ++s){
    int n0 = (s < 4) ? nu0 : nv0;
    int n1 = (s < 4) ? nu1 : nv1;
    int koff = (s & 3) * 32 + lk * 8;
    const float4* p0 = reinterpret_cast<const float4*>(&H[(size_t)n0 * D + koff]);
    const float4* p1 = reinterpret_cast<const float4*>(&H[(size_t)n1 * D + koff]);
    float4 a00 = p0[0], a01 = p0[1];
    float4 a10 = p1[0], a11 = p1[1];
    uint4 h0, l0, h1, l1;
    split8(a00, a01, h0, l0);
    split8(a10, a11, h1, l1);
    bf16x8 afh0 = *reinterpret_cast<bf16x8*>(&h0);
    bf16x8 afl0 = *reinterpret_cast<bf16x8*>(&l0);
    bf16x8 afh1 = *reinterpret_cast<bf16x8*>(&h1);
    bf16x8 afl1 = *reinterpret_cast<bf16x8*>(&l1);

    int k0 = s * 32 + lk * 8;
    #pragma unroll
    for (int f = 0; f < 4; ++f){
      int col = f * 16 + lm;
      bf16x8 bh = *reinterpret_cast<const bf16x8*>(&W0H[(size_t)col * 264 + k0]);
      bf16x8 bl = *reinterpret_cast<const bf16x8*>(&W0L[(size_t)col * 264 + k0]);
      acc[0][f] = __builtin_amdgcn_mfma_f32_16x16x32_bf16(afh0, bh, acc[0][f], 0, 0, 0);
      acc[0][f] = __builtin_amdgcn_mfma_f32_16x16x32_bf16(afl0, bh, acc[0][f], 0, 0, 0);
      acc[0][f] = __builtin_amdgcn_mfma_f32_16x16x32_bf16(afh0, bl, acc[0][f], 0, 0, 0);
      acc[1][f] = __builtin_amdgcn_mfma_f32_16x16x32_bf16(afh1, bh, acc[1][f], 0, 0, 0);
      acc[1][f] = __builtin_amdgcn_mfma_f32_16x16x32_bf16(afl1, bh, acc[1][f], 0, 0, 0);
      acc[1][f] = __builtin_amdgcn_mfma_f32_16x16x32_bf16(afh1, bl, acc[1][f], 0, 0, 0);
    }
  }

  // ---- L1 epilogue: bias + feat term + lrelu, write z hi/lo to LDS ----
  float cfv[2][4];
  #pragma unroll
  for (int m = 0; m < 2; ++m)
    #pragma unroll
    for (int r = 0; r < 4; ++r)
      cfv[m][r] = cf[min(candbase + m * 16 + lk * 4 + r, C - 1)];

  #pragma unroll
  for (int f = 0; f < 4; ++f){
    int col = f * 16 + lm;
    float b0v = mb0[col];
    float wfv = mw0[256 * 64 + col];
    #pragma unroll
    for (int m = 0; m < 2; ++m){
      #pragma unroll
      for (int r = 0; r < 4; ++r){
        int cl = m * 16 + lk * 4 + r;
        float z = lrelu(acc[m][f][r] + b0v + cfv[m][r] * wfv);
        unsigned short h16 = f2bf_rn(z);
        zh[wv][cl * 72 + col] = h16;
        zl[wv][cl * 72 + col] = f2bf_rn(z - bf2f(h16));
      }
    }
  }
  // wave-local LDS: hardware lgkmcnt ordering covers write->read, no barrier

  // ---- layer 2: K = 64 via MFMA ----
  f32x4 a2[2][4];
  #pragma unroll
  for (int m = 0; m < 2; ++m)
    #pragma unroll
    for (int f = 0; f < 4; ++f) a2[m][f] = (f32x4){0.f, 0.f, 0.f, 0.f};

  #pragma unroll
  for (int s2 = 0; s2 < 2; ++s2){
    int kk = s2 * 32 + lk * 8;
    bf16x8 azh0 = *reinterpret_cast<const bf16x8*>(&zh[wv][(0 * 16 + lm) * 72 + kk]);
    bf16x8 azl0 = *reinterpret_cast<const bf16x8*>(&zl[wv][(0 * 16 + lm) * 72 + kk]);
    bf16x8 azh1 = *reinterpret_cast<const bf16x8*>(&zh[wv][(1 * 16 + lm) * 72 + kk]);
    bf16x8 azl1 = *reinterpret_cast<const bf16x8*>(&zl[wv][(1 * 16 + lm) * 72 + kk]);
    #pragma unroll
    for (int f = 0; f < 4; ++f){
      int col = f * 16 + lm;
      bf16x8 bh = *reinterpret_cast<const bf16x8*>(&W1H[(size_t)col * 64 + kk]);
      bf16x8 bl = *reinterpret_cast<const bf16x8*>(&W1L[(size_t)col * 64 + kk]);
      a2[0][f] = __builtin_amdgcn_mfma_f32_16x16x32_bf16(azh0, bh, a2[0][f], 0, 0, 0);
      a2[0][f] = __builtin_amdgcn_mfma_f32_16x16x32_bf16(azl0, bh, a2[0][f], 0, 0, 0);
      a2[0][f] = __builtin_amdgcn_mfma_f32_16x16x32_bf16(azh0, bl, a2[0][f], 0, 0, 0);
      a2[1][f] = __builtin_amdgcn_mfma_f32_16x16x32_bf16(azh1, bh, a2[1][f], 0, 0, 0);
      a2[1][f] = __builtin_amdgcn_mfma_f32_16x16x32_bf16(azl1, bh, a2[1][f], 0, 0, 0);
      a2[1][f] = __builtin_amdgcn_mfma_f32_16x16x32_bf16(azh1, bl, a2[1][f], 0, 0, 0);
    }
  }

  // ---- layer 3: 64 -> 1 : per-lane partial + 16-lane xor reduce ----
  float p00 = 0.f, p01 = 0.f, p02 = 0.f, p03 = 0.f;
  float p10 = 0.f, p11 = 0.f, p12 = 0.f, p13 = 0.f;
  #pragma unroll
  for (int f = 0; f < 4; ++f){
    int col = f * 16 + lm;
    float b1v = mb1[col];
    float w2v = mw2[col];
    p00 = fmaf(lrelu(a2[0][f][0] + b1v), w2v, p00);
    p01 = fmaf(lrelu(a2[0][f][1] + b1v), w2v, p01);
    p02 = fmaf(lrelu(a2[0][f][2] + b1v), w2v, p02);
    p03 = fmaf(lrelu(a2[0][f][3] + b1v), w2v, p03);
    p10 = fmaf(lrelu(a2[1][f][0] + b1v), w2v, p10);
    p11 = fmaf(lrelu(a2[1][f][1] + b1v), w2v, p11);
    p12 = fmaf(lrelu(a2[1][f][2] + b1v), w2v, p12);
    p13 = fmaf(lrelu(a2[1][f][3] + b1v), w2v, p13);
  }
  #pragma unroll
  for (int off = 1; off < 16; off <<= 1){
    p00 += __shfl_xor(p00, off); p01 += __shfl_xor(p01, off);
    p02 += __shfl_xor(p02, off); p03 += __shfl_xor(p03, off);
    p10 += __shfl_xor(p10, off); p11 += __shfl_xor(p11, off);
    p12 += __shfl_xor(p12, off); p13 += __shfl_xor(p13, off);
  }
  if (lm == 0){
    float b2 = mb2[0];
    int base0 = candbase + lk * 4;
    int base1 = candbase + 16 + lk * 4;
    if (base0 + 0 < C) y[base0 + 0] = p00 + b2;
    if (base0 + 1 < C) y[base0 + 1] = p01 + b2;
    if (base0 + 2 < C) y[base0 + 2] = p02 + b2;
    if (base0 + 3 < C) y[base0 + 3] = p03 + b2;
    if (base1 + 0 < C) y[base1 + 0] = p10 + b2;
    if (base1 + 1 < C) y[base1 + 1] = p11 + b2;
    if (base1 + 2 < C) y[base1 + 2] = p12 + b2;
    if (base1 + 3 < C) y[base1 + 3] = p13 + b2;
  }
}

// ---------------- softmax over C logits ----------------
__global__ __launch_bounds__(256) void k_red1(const float* __restrict__ y,
                                              float* __restrict__ bmax, float* __restrict__ bsum, int C){
  __shared__ float sm[4];
  __shared__ float ss[4];
  int t = threadIdx.x;
  float m = -3.4e38f;
  for (int i = blockIdx.x * 256 + t; i < C; i += gridDim.x * 256) m = fmaxf(m, y[i]);
  for (int o = 32; o; o >>= 1) m = fmaxf(m, __shfl_xor(m, o));
  if ((t & 63) == 0) sm[t >> 6] = m;
  __syncthreads();
  float bm = fmaxf(fmaxf(sm[0], sm[1]), fmaxf(sm[2], sm[3]));
  float s = 0.f;
  for (int i = blockIdx.x * 256 + t; i < C; i += gridDim.x * 256) s += expf(y[i] - bm);
  for (int o = 32; o; o >>= 1) s += __shfl_xor(s, o);
  if ((t & 63) == 0) ss[t >> 6] = s;
  __syncthreads();
  if (t == 0){ bmax[blockIdx.x] = bm; bsum[blockIdx.x] = ss[0] + ss[1] + ss[2] + ss[3]; }
}

__global__ __launch_bounds__(256) void k_red2(const float* __restrict__ bmax, const float* __restrict__ bsum,
                                              float* __restrict__ g, int nb){
  __shared__ float sm[4];
  __shared__ float ss[4];
  int t = threadIdx.x;
  float m0 = (t < nb) ? bmax[t] : -3.4e38f;
  float m = m0;
  for (int o = 32; o; o >>= 1) m = fmaxf(m, __shfl_xor(m, o));
  if ((t & 63) == 0) sm[t >> 6] = m;
  __syncthreads();
  float gm = fmaxf(fmaxf(sm[0], sm[1]), fmaxf(sm[2], sm[3]));
  float s = (t < nb) ? bsum[t] * expf(m0 - gm) : 0.f;
  for (int o = 32; o; o >>= 1) s += __shfl_xor(s, o);
  if ((t & 63) == 0) ss[t >> 6] = s;
  __syncthreads();
  if (t == 0){ g[0] = gm; g[1] = 1.f / (ss[0] + ss[1] + ss[2] + ss[3]); }
}

__global__ __launch_bounds__(256) void k_red3(const float* __restrict__ y, const float* __restrict__ g,
                                              float* __restrict__ out, int C){
  int i = blockIdx.x * 256 + threadIdx.x;
  if (i < C) out[i] = expf(y[i] - g[0]) * g[1];
}

extern "C" void kernel_launch(void* const* d_in, const int* in_sizes, int n_in,
                              void* d_out, int out_size, void* d_ws, size_t ws_size,
                              hipStream_t stream)
{
  const float* x   = (const float*)d_in[0];
  const int*   src = (const int*)  d_in[1];
  const int*   dst = (const int*)  d_in[2];
  const int*   cu  = (const int*)  d_in[3];
  const int*   cv  = (const int*)  d_in[4];
  const float* cf  = (const float*)d_in[5];
  const float* ws0 = (const float*)d_in[6];
  const float* wn0 = (const float*)d_in[7];
  const float* b0  = (const float*)d_in[8];
  const float* g0  = (const float*)d_in[9];
  const float* be0 = (const float*)d_in[10];
  const float* rm0 = (const float*)d_in[11];
  const float* rv0 = (const float*)d_in[12];
  const float* ws1 = (const float*)d_in[13];
  const float* wn1 = (const float*)d_in[14];
  const float* b1  = (const float*)d_in[15];
  const float* g1  = (const float*)d_in[16];
  const float* be1 = (const float*)d_in[17];
  const float* rm1 = (const float*)d_in[18];
  const float* rv1 = (const float*)d_in[19];
  const float* mw0 = (const float*)d_in[20];
  const float* mb0 = (const float*)d_in[21];
  const float* mw1 = (const float*)d_in[22];
  const float* mb1 = (const float*)d_in[23];
  const float* mw2 = (const float*)d_in[24];
  const float* mb2 = (const float*)d_in[25];

  float* out = (float*)d_out;   // [C] y then [C] softmax

  char* w = (char*)d_ws;
  float* aggn  = (float*)w; w += (size_t)N_NODES * D * 4;
  float* h0    = (float*)w; w += (size_t)N_NODES * D * 4;
  float* h1    = (float*)w; w += (size_t)N_NODES * D * 4;
  int* cnt     = (int*)w;   w += (size_t)N_NODES * 4;
  int* rowptr  = (int*)w;   w += (size_t)(N_NODES + 1) * 4;
  int* cur     = (int*)w;   w += (size_t)N_NODES * 4;
  int* eid     = (int*)w;   w += (size_t)N_EDGES * 4;
  int* bsumI   = (int*)w;   w += 256 * 4;
  float* bmax  = (float*)w; w += 256 * 4;
  float* bsumF = (float*)w; w += 256 * 4;
  float* gred  = (float*)w; w += 2 * 4;
  // split MLP weights (transposed): w0 [64][264] hi/lo, w1 [64][64] hi/lo
  unsigned short* w0th = (unsigned short*)w; w += (size_t)64 * 264 * 2;
  unsigned short* w0tl = (unsigned short*)w; w += (size_t)64 * 264 * 2;
  unsigned short* w1th = (unsigned short*)w; w += (size_t)64 * 64 * 2;
  unsigned short* w1tl = (unsigned short*)w; w += (size_t)64 * 64 * 2;

  // bf16 gather planes OVERLAY the h1 region (zero extra workspace):
  //   xb  live [cvt_x .. agg0],  hb0 live [sage0 .. agg1],  h1 live [sage1 .. mlp]
  unsigned short* xb  = (unsigned short*)h1;
  unsigned short* hb0 = xb + (size_t)N_NODES * D;

  // split-bf16 SAGE weight buffers alias the CSR scratch dead after k_fill:
  unsigned short* bth0 = (unsigned short*)cnt;
  unsigned short* btl0 = bth0 + 128 * 256;
  unsigned short* bth1 = (unsigned short*)cur;
  unsigned short* btl1 = bth1 + 128 * 256;

  hipMemsetAsync(cnt, 0, (size_t)N_NODES * 4, stream);
  hipMemsetAsync(cur, 0, (size_t)N_NODES * 4, stream);

  int SB = (N_NODES + 255) / 256;   // 196
  k_hist <<<(N_EDGES + 255) / 256, 256, 0, stream>>>(dst, cnt, N_EDGES);
  k_scan1<<<SB, 256, 0, stream>>>(cnt, rowptr, bsumI, N_NODES);
  k_scan2<<<1, 256, 0, stream>>>(bsumI, rowptr, SB, N_NODES);
  k_scan3<<<SB, 256, 0, stream>>>(rowptr, bsumI, N_NODES);
  k_fill <<<(N_EDGES + 255) / 256, 256, 0, stream>>>(src, dst, rowptr, cur, eid, N_EDGES);

  // cnt/cur are dead now -> reuse for SAGE split weights
  k_cvt_w<<<128, 256, 0, stream>>>(ws0, wn0, bth0, btl0);
  k_cvt_w<<<128, 256, 0, stream>>>(ws1, wn1, bth1, btl1);
  k_cvt_mlp<<<64, 256, 0, stream>>>(mw0, 257, 264, w0th, w0tl);
  k_cvt_mlp<<<64, 256, 0, stream>>>(mw1, 64, 64, w1th, w1tl);
  k_cvt_x<<<(N_NODES * D / 4 + 255) / 256, 256, 0, stream>>>(x, xb, N_NODES * D / 4);

  int GB = (N_NODES + 63) / 64;     // 782
  k_agg_bf<<<(N_NODES + 7) / 8, 256, 0, stream>>>(xb, rowptr, eid, aggn, N_NODES);
  k_sage_mfma<<<GB, 256, 0, stream>>>(x,  aggn, bth0, btl0, b0, g0, be0, rm0, rv0, h0, hb0, N_NODES, 0);
  k_agg_bf<<<(N_NODES + 7) / 8, 256, 0, stream>>>(hb0, rowptr, eid, aggn, N_NODES);
  k_sage_mfma<<<GB, 256, 0, stream>>>(h0, aggn, bth1, btl1, b1, g1, be1, rm1, rv1, h1, (unsigned short*)0, N_NODES, 1);

  k_mlp_mfma<<<(N_CAND + 127) / 128, 256, 0, stream>>>(h1, cu, cv, cf,
      w0th, w0tl, mw0, mb0, w1th, w1tl, mb1, mw2, mb2, out, N_CAND);

  k_red1<<<256, 256, 0, stream>>>(out, bmax, bsumF, N_CAND);
  k_red2<<<1, 256, 0, stream>>>(bmax, bsumF, gred, 256);
  k_red3<<<(N_CAND + 255) / 256, 256, 0, stream>>>(out, gred, out + N_CAND, N_CAND);
}